// Round 15
// baseline (504.793 us; speedup 1.0000x reference)
//
#include <hip/hip_runtime.h>

#define DIMN 2048
#define NH 16
#define HDIM 128

typedef __attribute__((ext_vector_type(4))) float f32x4;
typedef __attribute__((ext_vector_type(16))) float f32x16;
typedef __attribute__((ext_vector_type(8))) __bf16 bfx8;
typedef __attribute__((ext_vector_type(4))) __bf16 bf16x4;
typedef __attribute__((ext_vector_type(8))) unsigned short u16x8;

__device__ __forceinline__ unsigned short f2bf(float f){
  unsigned u = __builtin_bit_cast(unsigned, f);
  u += 0x7fffu + ((u >> 16) & 1u);
  return (unsigned short)(u >> 16);
}
__device__ __forceinline__ float bf2f(unsigned short h){
  unsigned u = (unsigned)h << 16;
  return __builtin_bit_cast(float, u);
}

__device__ __forceinline__ void gl_lds16(const void* g, void* l){
  __builtin_amdgcn_global_load_lds((const __attribute__((address_space(1))) void*)g,
                                   (__attribute__((address_space(3))) void*)l, 16, 0, 0);
}

// m204 bijective XCD-chunked remap (works for any nwg)
__device__ __forceinline__ int xcd_swz(int bid, int nwg){
  const int q = nwg >> 3, r = nwg & 7;
  const int xcd = bid & 7, idx = bid >> 3;
  return (xcd < r ? xcd*(q+1) : r*(q+1) + (xcd-r)*q) + idx;
}

#define MFMA16(a,b,c) __builtin_amdgcn_mfma_f32_16x16x32_bf16((a),(b),(c),0,0,0)
#define MFMA32(a,b,c) __builtin_amdgcn_mfma_f32_32x32x16_bf16((a),(b),(c),0,0,0)

// ---------------- merged prep: casts + kcache relayout + v_cache transpose ----------
__global__ __launch_bounds__(256) void prep_kernel(const float* __restrict__ x,
    const float* __restrict__ Wq, const float* __restrict__ Wk, const float* __restrict__ Wv,
    const float* __restrict__ Wo, const float* __restrict__ k_cache,
    const float* __restrict__ v_cache,
    unsigned short* __restrict__ xb, unsigned short* __restrict__ Wqb,
    unsigned short* __restrict__ Wkb, unsigned short* __restrict__ Wvb,
    unsigned short* __restrict__ Wob, unsigned short* __restrict__ kb,
    unsigned short* __restrict__ vtb, int S_, int CACHE_, int L_){
  __shared__ __align__(16) unsigned short tile[32][72];
  const int WB = (DIMN*DIMN/8)/256;
  const int t = threadIdx.x;
  int bid = blockIdx.x;
  if (bid < S_){
    const size_t base = (size_t)bid*DIMN + t*8;
    const float4* p = (const float4*)(x + base);
    float4 a = p[0], b = p[1];
    u16x8 o;
    o[0]=f2bf(a.x); o[1]=f2bf(a.y); o[2]=f2bf(a.z); o[3]=f2bf(a.w);
    o[4]=f2bf(b.x); o[5]=f2bf(b.y); o[6]=f2bf(b.z); o[7]=f2bf(b.w);
    *(u16x8*)(xb + base) = o;
    return;
  }
  bid -= S_;
  if (bid < 4*WB){
    const int wsel = bid / WB;
    const int lb   = bid - wsel*WB;
    const float* in = (wsel==0) ? Wq : (wsel==1) ? Wk : (wsel==2) ? Wv : Wo;
    unsigned short* out = (wsel==0) ? Wqb : (wsel==1) ? Wkb : (wsel==2) ? Wvb : Wob;
    const size_t base = ((size_t)lb*256 + t)*8;
    const float4* p = (const float4*)(in + base);
    float4 a = p[0], b = p[1];
    u16x8 o;
    o[0]=f2bf(a.x); o[1]=f2bf(a.y); o[2]=f2bf(a.z); o[3]=f2bf(a.w);
    o[4]=f2bf(b.x); o[5]=f2bf(b.y); o[6]=f2bf(b.z); o[7]=f2bf(b.w);
    *(u16x8*)(out + base) = o;
    return;
  }
  bid -= 4*WB;
  if (bid < CACHE_){
    const size_t idx = ((size_t)bid*256 + t)*8;
    const int k   = (int)(idx >> 11);
    const int rem = (int)(idx & 2047);
    const int hh  = rem >> 7, d = rem & 127;
    const float4* p = (const float4*)(k_cache + idx);
    float4 a = p[0], b = p[1];
    u16x8 o;
    o[0]=f2bf(a.x); o[1]=f2bf(a.y); o[2]=f2bf(a.z); o[3]=f2bf(a.w);
    o[4]=f2bf(b.x); o[5]=f2bf(b.y); o[6]=f2bf(b.z); o[7]=f2bf(b.w);
    *(u16x8*)(kb + (size_t)hh*L_*HDIM + (size_t)k*HDIM + d) = o;
    return;
  }
  bid -= CACHE_;
  {
    const int nkb = (CACHE_ + 63) >> 6;
    const int kbi = bid % nkb;
    const int rest = bid / nkb;
    const int dbi = rest & 3;
    const int hh  = rest >> 2;
    const int kb0 = kbi * 64, db0 = dbi * 32;
    const int kk = t >> 2, dd = (t & 3) * 8;
    const int k = kb0 + kk;
    if (k < CACHE_){
      const float* p = v_cache + (size_t)k*DIMN + hh*HDIM + db0 + dd;
      float4 a = ((const float4*)p)[0], b = ((const float4*)p)[1];
      tile[dd+0][kk] = f2bf(a.x); tile[dd+1][kk] = f2bf(a.y);
      tile[dd+2][kk] = f2bf(a.z); tile[dd+3][kk] = f2bf(a.w);
      tile[dd+4][kk] = f2bf(b.x); tile[dd+5][kk] = f2bf(b.y);
      tile[dd+6][kk] = f2bf(b.z); tile[dd+7][kk] = f2bf(b.w);
    }
    __syncthreads();
    const int d = t >> 3, k0 = (t & 7) * 8;
    unsigned short* dst = vtb + (size_t)hh*HDIM*L_ + (size_t)(db0+d)*L_ + kb0 + k0;
    if (kb0 + k0 + 8 <= CACHE_){
      *(u16x8*)dst = *(const u16x8*)&tile[d][k0];
    } else {
      #pragma unroll
      for (int e=0;e<8;++e) if (kb0 + k0 + e < CACHE_) dst[e] = tile[d][k0+e];
    }
  }
}

// ---------------- vtrans bf16 source (projected V) ----------------
__global__ __launch_bounds__(256) void vtrans_bf16_kernel(const unsigned short* __restrict__ src,
    unsigned short* __restrict__ vt, int R, int koff, int L_){
  __shared__ __align__(16) unsigned short tile[32][72];
  const int kb0 = blockIdx.x * 64, db0 = blockIdx.y * 32, hh = blockIdx.z;
  const int t = threadIdx.x;
  const int kk = t >> 2, dd = (t & 3) * 8;
  const int k = kb0 + kk;
  if (k < R){
    u16x8 a = *(const u16x8*)(src + (size_t)k*DIMN + hh*HDIM + db0 + dd);
    #pragma unroll
    for (int e=0;e<8;++e) tile[dd+e][kk] = a[e];
  }
  __syncthreads();
  const int d = t >> 3, k0 = (t & 7) * 8;
  unsigned short* dst = vt + (size_t)hh*HDIM*L_ + (size_t)(db0+d)*L_ + koff + kb0 + k0;
  if (kb0 + k0 + 8 <= R){
    *(u16x8*)dst = *(const u16x8*)&tile[d][k0];
  } else {
    #pragma unroll
    for (int e=0;e<8;++e) if (kb0 + k0 + e < R) dst[e] = tile[d][k0+e];
  }
}

// ---------------- fused rmsnorm + RoPE; y=0: Q path, y=1: K path ----------------
__global__ __launch_bounds__(256) void norm_rope_kernel(const unsigned short* __restrict__ lin0,
    const unsigned short* __restrict__ lin1, const float* __restrict__ gq,
    const float* __restrict__ gk, const float* __restrict__ freqs, const int* __restrict__ cur,
    unsigned short* __restrict__ qb, unsigned short* __restrict__ kb,
    int S_, int CACHE_, int L_, float qsc){
  const int q = blockIdx.x, t = threadIdx.x;
  const int path = blockIdx.y;
  const unsigned short* lin = path ? lin1 : lin0;
  const float* g = path ? gk : gq;
  unsigned short* out = path ? kb : qb;
  const size_t head_stride = path ? (size_t)L_*HDIM : (size_t)S_*HDIM;
  const int row_off = path ? CACHE_ : 0;
  const float oscale = path ? 1.0f : qsc;
  u16x8 v = *(const u16x8*)(lin + (size_t)q*DIMN + t*8);
  float x[8];
  #pragma unroll
  for (int e=0;e<8;++e) x[e] = bf2f(v[e]);
  float ss = 0.f;
  #pragma unroll
  for (int e=0;e<8;++e) ss += x[e]*x[e];
  for (int m=1;m<64;m<<=1) ss += __shfl_xor(ss, m);
  __shared__ float red[4];
  if ((t & 63) == 0) red[t>>6] = ss;
  __syncthreads();
  const float tot = red[0]+red[1]+red[2]+red[3];
  const float rstd = rsqrtf(tot * (1.0f/2048.0f) + 1e-6f);
  const int n0 = t*8;
  float xr[8];
  #pragma unroll
  for (int e=0;e<8;++e) xr[e] = x[e] * rstd * g[n0+e];
  const int pos = cur[0] + q;
  const int hh = n0 >> 7, d0 = n0 & 127;
  const float* fr = freqs + (size_t)pos * HDIM;
  float o[8];
  #pragma unroll
  for (int p=0;p<4;++p){
    const int j = (d0>>1) + p;
    const float c = fr[j], s = fr[64+j];
    o[2*p]   = xr[2*p]*c - xr[2*p+1]*s;
    o[2*p+1] = xr[2*p+1]*c + xr[2*p]*s;
  }
  u16x8 ov;
  #pragma unroll
  for (int e=0;e<8;++e) ov[e] = f2bf(o[e]*oscale);
  *(u16x8*)(out + (size_t)hh*head_stride + (size_t)(q+row_off)*HDIM + d0) = ov;
}

// ---------------- C[M,N] = A[M,K] * B[N,K]^T + bias, bf16 in fp32 out ----------------
__global__ __launch_bounds__(256,2) void gemm_bt(const unsigned short* __restrict__ A,
    const unsigned short* __restrict__ B, const float* __restrict__ bias,
    float* __restrict__ C, int M, int N, int K){
  __shared__ __align__(16) unsigned short As[2][128*64];
  __shared__ __align__(16) unsigned short Bs[2][128*64];
  const int mb = (M + 127) >> 7;
  const int swz = xcd_swz(blockIdx.x, gridDim.x);
  const int bx = swz / mb, by = swz % mb;
  const int t = threadIdx.x;
  const int w = t >> 6, lane = t & 63, lh = lane >> 4, ll = lane & 15;
  const int wr = w >> 1, wc = w & 1;
  const int m0 = by * 128, n0 = bx * 128;
  const int srow = t >> 3;
  const int scb  = (t & 7) * 16;
  const int swc  = (scb ^ ((srow & 7) << 4)) >> 1;
  int arow[4]; size_t brow[4];
  #pragma unroll
  for (int c=0;c<4;++c){
    int r = m0 + c*32 + srow; if (r >= M) r = M-1;
    arow[c] = r;
    brow[c] = (size_t)(n0 + c*32 + srow);
  }
  const int xsw = (ll & 7) << 4;
  f32x4 acc[4][4] = {};
  const int nk = K >> 6;
  auto stage = [&](int b, int kt){
    const int k0 = kt << 6;
    #pragma unroll
    for (int c=0;c<4;++c){
      gl_lds16(A + (size_t)arow[c]*K + k0 + swc, (char*)As[b] + c*4096 + w*1024);
      gl_lds16(B + brow[c]*K       + k0 + swc, (char*)Bs[b] + c*4096 + w*1024);
    }
  };
  stage(0, 0);
  asm volatile("s_waitcnt vmcnt(0)" ::: "memory");
  __syncthreads();
  int cur = 0;
  for (int kt = 0; kt < nk; ++kt){
    if (kt + 1 < nk) stage(cur ^ 1, kt + 1);
    #pragma unroll
    for (int kk=0;kk<2;++kk){
      const int cb = kk*64 + lh*16;
      bfx8 a[4], b[4];
      #pragma unroll
      for (int i=0;i<4;++i)
        a[i] = *(const bfx8*)((const char*)As[cur] + (wr*64 + i*16 + ll)*128 + (cb ^ xsw));
      #pragma unroll
      for (int j=0;j<4;++j)
        b[j] = *(const bfx8*)((const char*)Bs[cur] + (wc*64 + j*16 + ll)*128 + (cb ^ xsw));
      __builtin_amdgcn_s_setprio(1);
      #pragma unroll
      for (int i=0;i<4;++i)
        #pragma unroll
        for (int j=0;j<4;++j)
          acc[i][j] = MFMA16(a[i], b[j], acc[i][j]);
      __builtin_amdgcn_s_setprio(0);
    }
    asm volatile("s_waitcnt vmcnt(0)" ::: "memory");
    __syncthreads();
    cur ^= 1;
  }
  #pragma unroll
  for (int i=0;i<4;++i){
    #pragma unroll
    for (int j=0;j<4;++j){
      const int col = n0 + wc*64 + j*16 + ll;
      const float bb = bias[col];
      #pragma unroll
      for (int r=0;r<4;++r){
        const int row = m0 + wr*64 + i*16 + lh*4 + r;
        if (row < M) C[(size_t)row*N + col] = acc[i][j][r] + bb;
      }
    }
  }
}

// ---------------- fused QKV gemm (1D grid + XCD swizzle); dbuf; bf16 out ----------------
__global__ __launch_bounds__(256,2) void gemm_qkv(const unsigned short* __restrict__ A,
    const unsigned short* __restrict__ B0, const unsigned short* __restrict__ B1,
    const unsigned short* __restrict__ B2, const float* __restrict__ g0,
    const float* __restrict__ g1, const float* __restrict__ g2,
    unsigned short* __restrict__ C0, unsigned short* __restrict__ C1,
    unsigned short* __restrict__ C2, int M, int N, int K){
  const int mb = (M + 127) >> 7;
  const int nxt = N >> 7;
  const int per = nxt * mb;
  const int swz = xcd_swz(blockIdx.x, gridDim.x);
  const int zz = swz / per;
  const int rem = swz - zz * per;
  const int bx = rem / mb, by = rem % mb;
  const unsigned short* B = (zz==0) ? B0 : (zz==1) ? B1 : B2;
  const float* bias       = (zz==0) ? g0 : (zz==1) ? g1 : g2;
  unsigned short* C       = (zz==0) ? C0 : (zz==1) ? C1 : C2;
  __shared__ __align__(16) unsigned short As[2][128*64];
  __shared__ __align__(16) unsigned short Bs[2][128*64];
  const int t = threadIdx.x;
  const int w = t >> 6, lane = t & 63, lh = lane >> 4, ll = lane & 15;
  const int wr = w >> 1, wc = w & 1;
  const int m0 = by * 128, n0 = bx * 128;
  const int srow = t >> 3;
  const int scb  = (t & 7) * 16;
  const int swc  = (scb ^ ((srow & 7) << 4)) >> 1;
  int arow[4]; size_t brow[4];
  #pragma unroll
  for (int c=0;c<4;++c){
    int r = m0 + c*32 + srow; if (r >= M) r = M-1;
    arow[c] = r;
    brow[c] = (size_t)(n0 + c*32 + srow);
  }
  const int xsw = (ll & 7) << 4;
  f32x4 acc[4][4] = {};
  const int nk = K >> 6;
  auto stage = [&](int b, int kt){
    const int k0 = kt << 6;
    #pragma unroll
    for (int c=0;c<4;++c){
      gl_lds16(A + (size_t)arow[c]*K + k0 + swc, (char*)As[b] + c*4096 + w*1024);
      gl_lds16(B + brow[c]*K       + k0 + swc, (char*)Bs[b] + c*4096 + w*1024);
    }
  };
  stage(0, 0);
  asm volatile("s_waitcnt vmcnt(0)" ::: "memory");
  __syncthreads();
  int cur = 0;
  for (int kt = 0; kt < nk; ++kt){
    if (kt + 1 < nk) stage(cur ^ 1, kt + 1);
    #pragma unroll
    for (int kk=0;kk<2;++kk){
      const int cb = kk*64 + lh*16;
      bfx8 a[4], b[4];
      #pragma unroll
      for (int i=0;i<4;++i)
        a[i] = *(const bfx8*)((const char*)As[cur] + (wr*64 + i*16 + ll)*128 + (cb ^ xsw));
      #pragma unroll
      for (int j=0;j<4;++j)
        b[j] = *(const bfx8*)((const char*)Bs[cur] + (wc*64 + j*16 + ll)*128 + (cb ^ xsw));
      __builtin_amdgcn_s_setprio(1);
      #pragma unroll
      for (int i=0;i<4;++i)
        #pragma unroll
        for (int j=0;j<4;++j)
          acc[i][j] = MFMA16(a[i], b[j], acc[i][j]);
      __builtin_amdgcn_s_setprio(0);
    }
    asm volatile("s_waitcnt vmcnt(0)" ::: "memory");
    __syncthreads();
    cur ^= 1;
  }
  #pragma unroll
  for (int i=0;i<4;++i){
    #pragma unroll
    for (int j=0;j<4;++j){
      const int col = n0 + wc*64 + j*16 + ll;
      const float bb = bias[col];
      #pragma unroll
      for (int r=0;r<4;++r){
        const int row = m0 + wr*64 + i*16 + lh*4 + r;
        if (row < M) C[(size_t)row*N + col] = f2bf(acc[i][j][r] + bb);
      }
    }
  }
}

// ---------------- flash attention: 4 waves, 32x32x16, 48KB LDS, 2-raw-barrier pipe ----
// Single-buffered Ks/Vs (16K each) + Ps (16K) = 48KB -> 3 blocks/CU.
// Schedule per tile (counted waits, raw s_barrier — no __syncthreads full drain):
//   [Ks holds K(kt) landed; V(kt) DMA flying]
//   QK^T(Ks) -> wait vmcnt0+lgkm0 -> bar BC -> issue K-DMA(kt+1)
//   -> softmax + P + PV(Vs) -> wait vmcnt0+lgkm0 -> bar D -> issue V-DMA(kt+1)
// launch_bounds(256,3): cap 170 regs (arch ~106 + 64 acc) for 3 waves/SIMD.
__global__ __launch_bounds__(256,3) void attn_kernel(const unsigned short* __restrict__ Q,
    const unsigned short* __restrict__ K, const unsigned short* __restrict__ VT,
    unsigned short* __restrict__ O, float* __restrict__ pacc, float* __restrict__ pml,
    int S_, int L_, int CLn, int nx, int nsplit){
  __shared__ __align__(16) unsigned short Ks[64*128];
  __shared__ __align__(16) unsigned short Vs[128*64];
  __shared__ __align__(16) unsigned short Ps[4][32*64];
  const int nwg = gridDim.x;
  const int swzid = (blockIdx.x & 7)*(nwg >> 3) + (blockIdx.x >> 3);
  const int xq = swzid % nx;
  const int rest = swzid / nx;
  const int hh = rest % NH;
  const int z  = rest / NH;
  const int q0 = xq * 128;
  const int t = threadIdx.x, w = t >> 6, lane = t & 63;
  const int l31 = lane & 31, h = lane >> 5;
  char* Pw = (char*)Ps[w];
  const int xswp = (l31 & 7) << 4;
  const unsigned short* Qh = Q  + (size_t)hh*S_*HDIM;
  const unsigned short* Kh = K  + (size_t)hh*L_*HDIM;
  const unsigned short* Vh = VT + (size_t)hh*HDIM*L_;
  const int wrow0 = q0 + w*32;
  const int myq = wrow0 + l31;
  bfx8 qf[8];
  {
    int qr = myq; if (qr >= S_) qr = S_ - 1;
    #pragma unroll
    for (int kk=0;kk<8;++kk)
      qf[kk] = *(const bfx8*)(Qh + (size_t)qr*HDIM + kk*16 + h*8);
  }
  f32x16 acc[4] = {};
  float m_st = -1e20f, l_st = 0.f;
  int qlast = q0 + 127; if (qlast >= S_) qlast = S_ - 1;
  const int kend = CLn + qlast + 1;
  const int nt = (kend + 63) >> 6;
  const int tps = (nt + nsplit - 1) / nsplit;
  const int t0 = z * tps;
  int t1 = t0 + tps; if (t1 > nt) t1 = nt;
  const int ksrow = t >> 4;
  const int kswc  = (((t & 15)*16) ^ ((ksrow & 7) << 4)) >> 1;
  const int vsrow = t >> 3;
  const int vswc  = (((t & 7)*16) ^ ((vsrow & 7) << 4)) >> 1;

  auto stage_K = [&](int ktile){
    const int kv0 = ktile << 6;
    #pragma unroll
    for (int c=0;c<4;++c)
      gl_lds16(Kh + (size_t)(kv0 + c*16 + ksrow)*HDIM + kswc, (char*)Ks + c*4096 + w*1024);
  };
  auto stage_V = [&](int ktile){
    const int kv0 = ktile << 6;
    #pragma unroll
    for (int c=0;c<4;++c)
      gl_lds16(Vh + (size_t)(c*32 + vsrow)*L_ + kv0 + vswc, (char*)Vs + c*4096 + w*1024);
  };

  // prologue: K(t0) then V(t0); wait K landed (V keeps flying), barrier
  if (t0 < t1){ stage_K(t0); stage_V(t0); }
  asm volatile("s_waitcnt vmcnt(4)" ::: "memory");
  __builtin_amdgcn_sched_barrier(0);
  __builtin_amdgcn_s_barrier();

  const int krow0 = l31,      koff0 = (krow0 & 7) << 4;
  const int krow1 = 32 + l31, koff1 = (krow1 & 7) << 4;
  for (int kt = t0; kt < t1; ++kt){
    const int kv0 = kt << 6;
    // QK^T on Ks (landed for all threads)
    f32x16 sc0 = {}, sc1 = {};
    __builtin_amdgcn_s_setprio(1);
    #pragma unroll
    for (int kk=0;kk<8;++kk){
      const int cb = kk*32 + h*16;
      bfx8 kf0 = *(const bfx8*)((const char*)Ks + krow0*256 + (cb ^ koff0));
      bfx8 kf1 = *(const bfx8*)((const char*)Ks + krow1*256 + (cb ^ koff1));
      sc0 = MFMA32(kf0, qf[kk], sc0);
      sc1 = MFMA32(kf1, qf[kk], sc1);
    }
    __builtin_amdgcn_s_setprio(0);
    // V(kt) landed + my Ks reads done -> barrier BC
    asm volatile("s_waitcnt vmcnt(0) lgkmcnt(0)" ::: "memory");
    __builtin_amdgcn_sched_barrier(0);
    __builtin_amdgcn_s_barrier();
    if (kt + 1 < t1) stage_K(kt + 1);   // K-DMA flies under softmax+PV
    // causal mask (scale*log2e folded into Q)
    if (kv0 + 63 > CLn + wrow0){
      const int lim = CLn + myq;
      #pragma unroll
      for (int r=0;r<16;++r){
        const int kl = (r&3) + 8*(r>>2) + 4*h;
        if (kv0 + kl      > lim) sc0[r] = -1e30f;
        if (kv0 + 32 + kl > lim) sc1[r] = -1e30f;
      }
    }
    // row max
    float mt = sc0[0];
    #pragma unroll
    for (int r=1;r<15;r+=2) mt = fmaxf(fmaxf(sc0[r], sc0[r+1]), mt);
    mt = fmaxf(sc0[15], mt);
    #pragma unroll
    for (int r=0;r<16;r+=2) mt = fmaxf(fmaxf(sc1[r], sc1[r+1]), mt);
    mt = fmaxf(mt, __shfl_xor(mt, 32));
    mt = fmaxf(mt, -1e20f);
    if (!__all(mt - m_st <= 11.54f)){
      const float mn = fmaxf(m_st, mt);
      const float corr = exp2f(m_st - mn);
      m_st = mn;
      l_st *= corr;
      #pragma unroll
      for (int r=0;r<16;++r){
        const int qrow = (r&3) + 8*(r>>2) + 4*h;
        const float ca = __shfl(corr, qrow);
        #pragma unroll
        for (int db=0;db<4;++db) acc[db][r] *= ca;
      }
    }
    float rs = 0.f;
    #pragma unroll
    for (int r=0;r<16;++r){
      const float p0 = exp2f(sc0[r] - m_st);
      const float p1 = exp2f(sc1[r] - m_st);
      sc0[r] = p0; sc1[r] = p1;
      rs += p0 + p1;
    }
    rs += __shfl_xor(rs, 32);
    l_st += rs;
    // P -> wave-private LDS (b64)
    #pragma unroll
    for (int i=0;i<4;++i){
      bf16x4 p0 = { (__bf16)sc0[4*i], (__bf16)sc0[4*i+1], (__bf16)sc0[4*i+2], (__bf16)sc0[4*i+3] };
      bf16x4 p1 = { (__bf16)sc1[4*i], (__bf16)sc1[4*i+1], (__bf16)sc1[4*i+2], (__bf16)sc1[4*i+3] };
      const int kb0b = (8*i + 4*h) * 2;
      *(bf16x4*)(Pw + l31*128 + (kb0b        ^ xswp)) = p0;
      *(bf16x4*)(Pw + l31*128 + ((64 + kb0b) ^ xswp)) = p1;
    }
    // PV on Vs (landed)
    __builtin_amdgcn_s_setprio(1);
    #pragma unroll
    for (int s=0;s<4;++s){
      bfx8 pa = *(const bfx8*)(Pw + l31*128 + ((s*32 + h*16) ^ xswp));
      const int vb = s*32 + h*16;
      #pragma unroll
      for (int db=0;db<4;++db){
        const int vrow = db*32 + l31;
        bfx8 vf = *(const bfx8*)((const char*)Vs + vrow*128 + (vb ^ ((vrow & 7) << 4)));
        acc[db] = MFMA32(pa, vf, acc[db]);
      }
    }
    __builtin_amdgcn_s_setprio(0);
    // K(kt+1) landed + my Vs/Ps ops done -> barrier D
    asm volatile("s_waitcnt vmcnt(0) lgkmcnt(0)" ::: "memory");
    __builtin_amdgcn_sched_barrier(0);
    __builtin_amdgcn_s_barrier();
    if (kt + 1 < t1) stage_V(kt + 1);   // V-DMA flies under next QK^T
  }
  // epilogue
  if (nsplit == 1){
    const float linv = 1.0f / l_st;
    #pragma unroll
    for (int r=0;r<16;++r){
      const int qrow = (r&3) + 8*(r>>2) + 4*h;
      const float inv = __shfl(linv, qrow);
      const int qr = wrow0 + qrow;
      if (qr < S_){
        #pragma unroll
        for (int db=0;db<4;++db)
          O[(size_t)qr*DIMN + hh*HDIM + db*32 + l31] = f2bf(acc[db][r]*inv);
      }
    }
  } else {
    #pragma unroll
    for (int r=0;r<16;++r){
      const int qrow = (r&3) + 8*(r>>2) + 4*h;
      const int qr = wrow0 + qrow;
      if (qr < S_){
        const size_t rid = ((size_t)z*NH + hh)*S_ + qr;
        float* dst = pacc + rid*128;
        #pragma unroll
        for (int db=0;db<4;++db) dst[db*32 + l31] = acc[db][r];
      }
    }
    if (lane < 32 && myq < S_){
      const size_t rid2 = ((size_t)z*NH + hh)*S_ + myq;
      pml[rid2*2]   = m_st;
      pml[rid2*2+1] = l_st;
    }
  }
}

// ---------------- combine partials -> ob bf16 (exp2 domain m) ----------------
__global__ __launch_bounds__(256) void combine_kernel(const float* __restrict__ pacc,
    const float* __restrict__ pml, unsigned short* __restrict__ ob, int S_, int nsplit){
  const int t = threadIdx.x;
  const int rid = blockIdx.x*2 + (t >> 7);
  if (rid >= S_*NH) return;
  const int d = t & 127;
  const int hh = rid / S_;
  const int q  = rid - hh*S_;
  float M = -1e20f;
  for (int s=0; s<nsplit; ++s)
    M = fmaxf(M, pml[((size_t)s*NH*S_ + rid)*2]);
  float lt = 0.f, o = 0.f;
  for (int s=0; s<nsplit; ++s){
    const float m = pml[((size_t)s*NH*S_ + rid)*2];
    const float l = pml[((size_t)s*NH*S_ + rid)*2 + 1];
    const float wgt = exp2f(m - M);
    lt += l * wgt;
    o  += pacc[((size_t)s*NH*S_ + rid)*128 + d] * wgt;
  }
  if (lt == 0.f) lt = 1.f;
  ob[(size_t)q*DIMN + hh*HDIM + d] = f2bf(o / lt);
}

extern "C" void kernel_launch(void* const* d_in, const int* in_sizes, int n_in,
                              void* d_out, int out_size, void* d_ws, size_t ws_size,
                              hipStream_t stream){
  const float* x       = (const float*)d_in[0];
  const float* freqs   = (const float*)d_in[1];
  const float* k_cache = (const float*)d_in[2];
  const float* v_cache = (const float*)d_in[3];
  const float* Wq = (const float*)d_in[4];
  const float* bq = (const float*)d_in[5];
  const float* Wk = (const float*)d_in[6];
  const float* bk = (const float*)d_in[7];
  const float* Wv = (const float*)d_in[8];
  const float* bv = (const float*)d_in[9];
  const float* Wo = (const float*)d_in[10];
  const float* bo = (const float*)d_in[11];
  const float* gq = (const float*)d_in[12];
  const float* gk = (const float*)d_in[13];
  const int*   cur = (const int*)d_in[14];

  const int S = in_sizes[0] / DIMN;
  const int CACHE_ = in_sizes[2] / DIMN;
  const int L = CACHE_ + S;
  const int CLn = L - S;

  auto al = [](size_t n){ return (n + 255) & ~(size_t)255; };
  char* base = (char*)d_ws;
  size_t off = 0;
  auto take = [&](size_t n){ char* r = base + off; off += al(n); return r; };
  unsigned short* xb  = (unsigned short*)take((size_t)S*DIMN*2);
  unsigned short* Wob = (unsigned short*)take((size_t)DIMN*DIMN*2);
  unsigned short* qb  = (unsigned short*)take((size_t)NH*S*HDIM*2);
  unsigned short* kb  = (unsigned short*)take((size_t)NH*L*HDIM*2);
  unsigned short* vtb = (unsigned short*)take((size_t)NH*HDIM*L*2);
  unsigned short* ob  = (unsigned short*)take((size_t)S*DIMN*2);
  const size_t ubase = off;
  const size_t l_sz = al((size_t)S*DIMN*2);
  const size_t w_sz = al((size_t)DIMN*DIMN*2);
  unsigned short* lin0 = (unsigned short*)(base + ubase);
  unsigned short* lin1 = (unsigned short*)(base + ubase + l_sz);
  unsigned short* lin2 = (unsigned short*)(base + ubase + 2*l_sz);
  unsigned short* Wqb  = (unsigned short*)(base + ubase + 3*l_sz);
  unsigned short* Wkb  = (unsigned short*)(base + ubase + 3*l_sz + w_sz);
  unsigned short* Wvb  = (unsigned short*)(base + ubase + 3*l_sz + 2*w_sz);
  const size_t trans_sz = 3*l_sz + 3*w_sz;
  auto pool_sz = [&](int ns){
    return al((size_t)ns*NH*S*HDIM*4) + al((size_t)ns*NH*S*2*4);
  };
  int nsplit = 1;
  if (ubase + (trans_sz > pool_sz(4) ? trans_sz : pool_sz(4)) <= ws_size) nsplit = 4;
  else if (ubase + (trans_sz > pool_sz(2) ? trans_sz : pool_sz(2)) <= ws_size) nsplit = 2;
  if (ubase + trans_sz > ws_size) return;
  float* pacc = (float*)(base + ubase);
  float* pml  = (float*)(base + ubase + al((size_t)nsplit*NH*S*HDIM*4));

  const int WB = (DIMN*DIMN/8)/256;
  const int nkb = (CACHE_ + 63) >> 6;
  const int prep_blocks = S + 4*WB + CACHE_ + nkb*4*NH;
  prep_kernel<<<prep_blocks, 256, 0, stream>>>(x, Wq, Wk, Wv, Wo, k_cache, v_cache,
                                               xb, Wqb, Wkb, Wvb, Wob, kb, vtb,
                                               S, CACHE_, L);

  const int mb = (S+127)/128;
  gemm_qkv<<<(DIMN/128)*mb*3, 256, 0, stream>>>(xb, Wqb, Wkb, Wvb, bq, bk, bv,
                                                lin0, lin1, lin2, S, DIMN, DIMN);
  const float qsc = 0.08838834764831845f * 1.4426950408889634f;
  norm_rope_kernel<<<dim3(S,2), 256, 0, stream>>>(lin0, lin1, gq, gk, freqs, cur,
                                                  qb, kb, S, CACHE_, L, qsc);
  vtrans_bf16_kernel<<<dim3((S+63)/64, 4, NH), 256, 0, stream>>>(lin2, vtb, S, CACHE_, L);

  const int nx = (S+127)/128;
  attn_kernel<<<nx*NH*nsplit, 256, 0, stream>>>(qb, kb, vtb, ob,
                                                pacc, pml, S, L, CLn, nx, nsplit);
  if (nsplit > 1)
    combine_kernel<<<(S*NH+1)/2, 256, 0, stream>>>(pacc, pml, ob, S, nsplit);
  gemm_bt<<<(DIMN/128)*mb, 256, 0, stream>>>(ob, Wob, bo, (float*)d_out, S, DIMN, DIMN);
}

// Round 16
// 473.023 us; speedup vs baseline: 1.0672x; 1.0672x over previous
//
#include <hip/hip_runtime.h>

#define DIMN 2048
#define NH 16
#define HDIM 128

typedef __attribute__((ext_vector_type(4))) float f32x4;
typedef __attribute__((ext_vector_type(16))) float f32x16;
typedef __attribute__((ext_vector_type(8))) __bf16 bfx8;
typedef __attribute__((ext_vector_type(4))) __bf16 bf16x4;
typedef __attribute__((ext_vector_type(8))) unsigned short u16x8;

__device__ __forceinline__ unsigned short f2bf(float f){
  unsigned u = __builtin_bit_cast(unsigned, f);
  u += 0x7fffu + ((u >> 16) & 1u);
  return (unsigned short)(u >> 16);
}
__device__ __forceinline__ float bf2f(unsigned short h){
  unsigned u = (unsigned)h << 16;
  return __builtin_bit_cast(float, u);
}

__device__ __forceinline__ void gl_lds16(const void* g, void* l){
  __builtin_amdgcn_global_load_lds((const __attribute__((address_space(1))) void*)g,
                                   (__attribute__((address_space(3))) void*)l, 16, 0, 0);
}

// m204 bijective XCD-chunked remap (works for any nwg)
__device__ __forceinline__ int xcd_swz(int bid, int nwg){
  const int q = nwg >> 3, r = nwg & 7;
  const int xcd = bid & 7, idx = bid >> 3;
  return (xcd < r ? xcd*(q+1) : r*(q+1) + (xcd-r)*q) + idx;
}

#define MFMA16(a,b,c) __builtin_amdgcn_mfma_f32_16x16x32_bf16((a),(b),(c),0,0,0)
#define MFMA32(a,b,c) __builtin_amdgcn_mfma_f32_32x32x16_bf16((a),(b),(c),0,0,0)

// ---------------- merged prep: casts + kcache relayout + v_cache transpose ----------
// sections by blockIdx.x range (block-uniform): [0,S) x-cast; [S,S+4*2048) W casts;
// [.., +CACHE) kcache; [.., +nkb*4*NH) vtrans of v_cache.
__global__ __launch_bounds__(256) void prep_kernel(const float* __restrict__ x,
    const float* __restrict__ Wq, const float* __restrict__ Wk, const float* __restrict__ Wv,
    const float* __restrict__ Wo, const float* __restrict__ k_cache,
    const float* __restrict__ v_cache,
    unsigned short* __restrict__ xb, unsigned short* __restrict__ Wqb,
    unsigned short* __restrict__ Wkb, unsigned short* __restrict__ Wvb,
    unsigned short* __restrict__ Wob, unsigned short* __restrict__ kb,
    unsigned short* __restrict__ vtb, int S_, int CACHE_, int L_){
  __shared__ __align__(16) unsigned short tile[32][72];
  const int WB = (DIMN*DIMN/8)/256;   // 2048 blocks per weight
  const int t = threadIdx.x;
  int bid = blockIdx.x;
  if (bid < S_){
    // ---- x cast: one block per row ----
    const size_t base = (size_t)bid*DIMN + t*8;
    const float4* p = (const float4*)(x + base);
    float4 a = p[0], b = p[1];
    u16x8 o;
    o[0]=f2bf(a.x); o[1]=f2bf(a.y); o[2]=f2bf(a.z); o[3]=f2bf(a.w);
    o[4]=f2bf(b.x); o[5]=f2bf(b.y); o[6]=f2bf(b.z); o[7]=f2bf(b.w);
    *(u16x8*)(xb + base) = o;
    return;
  }
  bid -= S_;
  if (bid < 4*WB){
    // ---- weight casts ----
    const int wsel = bid / WB;
    const int lb   = bid - wsel*WB;
    const float* in = (wsel==0) ? Wq : (wsel==1) ? Wk : (wsel==2) ? Wv : Wo;
    unsigned short* out = (wsel==0) ? Wqb : (wsel==1) ? Wkb : (wsel==2) ? Wvb : Wob;
    const size_t base = ((size_t)lb*256 + t)*8;
    const float4* p = (const float4*)(in + base);
    float4 a = p[0], b = p[1];
    u16x8 o;
    o[0]=f2bf(a.x); o[1]=f2bf(a.y); o[2]=f2bf(a.z); o[3]=f2bf(a.w);
    o[4]=f2bf(b.x); o[5]=f2bf(b.y); o[6]=f2bf(b.z); o[7]=f2bf(b.w);
    *(u16x8*)(out + base) = o;
    return;
  }
  bid -= 4*WB;
  if (bid < CACHE_){
    // ---- kcache relayout: one block per key row ----
    const size_t idx = ((size_t)bid*256 + t)*8;
    const int k   = (int)(idx >> 11);
    const int rem = (int)(idx & 2047);
    const int hh  = rem >> 7, d = rem & 127;
    const float4* p = (const float4*)(k_cache + idx);
    float4 a = p[0], b = p[1];
    u16x8 o;
    o[0]=f2bf(a.x); o[1]=f2bf(a.y); o[2]=f2bf(a.z); o[3]=f2bf(a.w);
    o[4]=f2bf(b.x); o[5]=f2bf(b.y); o[6]=f2bf(b.z); o[7]=f2bf(b.w);
    *(u16x8*)(kb + (size_t)hh*L_*HDIM + (size_t)k*HDIM + d) = o;
    return;
  }
  bid -= CACHE_;
  {
    // ---- v_cache transpose -> vt[h][d][k] ----
    const int nkb = (CACHE_ + 63) >> 6;
    const int kbi = bid % nkb;
    const int rest = bid / nkb;
    const int dbi = rest & 3;
    const int hh  = rest >> 2;
    const int kb0 = kbi * 64, db0 = dbi * 32;
    const int kk = t >> 2, dd = (t & 3) * 8;
    const int k = kb0 + kk;
    if (k < CACHE_){
      const float* p = v_cache + (size_t)k*DIMN + hh*HDIM + db0 + dd;
      float4 a = ((const float4*)p)[0], b = ((const float4*)p)[1];
      tile[dd+0][kk] = f2bf(a.x); tile[dd+1][kk] = f2bf(a.y);
      tile[dd+2][kk] = f2bf(a.z); tile[dd+3][kk] = f2bf(a.w);
      tile[dd+4][kk] = f2bf(b.x); tile[dd+5][kk] = f2bf(b.y);
      tile[dd+6][kk] = f2bf(b.z); tile[dd+7][kk] = f2bf(b.w);
    }
    __syncthreads();
    const int d = t >> 3, k0 = (t & 7) * 8;
    unsigned short* dst = vtb + (size_t)hh*HDIM*L_ + (size_t)(db0+d)*L_ + kb0 + k0;
    if (kb0 + k0 + 8 <= CACHE_){
      *(u16x8*)dst = *(const u16x8*)&tile[d][k0];
    } else {
      #pragma unroll
      for (int e=0;e<8;++e) if (kb0 + k0 + e < CACHE_) dst[e] = tile[d][k0+e];
    }
  }
}

// ---------------- vtrans bf16 source (projected V) ----------------
__global__ __launch_bounds__(256) void vtrans_bf16_kernel(const unsigned short* __restrict__ src,
    unsigned short* __restrict__ vt, int R, int koff, int L_){
  __shared__ __align__(16) unsigned short tile[32][72];
  const int kb0 = blockIdx.x * 64, db0 = blockIdx.y * 32, hh = blockIdx.z;
  const int t = threadIdx.x;
  const int kk = t >> 2, dd = (t & 3) * 8;
  const int k = kb0 + kk;
  if (k < R){
    u16x8 a = *(const u16x8*)(src + (size_t)k*DIMN + hh*HDIM + db0 + dd);
    #pragma unroll
    for (int e=0;e<8;++e) tile[dd+e][kk] = a[e];
  }
  __syncthreads();
  const int d = t >> 3, k0 = (t & 7) * 8;
  unsigned short* dst = vt + (size_t)hh*HDIM*L_ + (size_t)(db0+d)*L_ + koff + kb0 + k0;
  if (kb0 + k0 + 8 <= R){
    *(u16x8*)dst = *(const u16x8*)&tile[d][k0];
  } else {
    #pragma unroll
    for (int e=0;e<8;++e) if (kb0 + k0 + e < R) dst[e] = tile[d][k0+e];
  }
}

// ---------------- fused rmsnorm + RoPE; y=0: Q path, y=1: K path ----------------
__global__ __launch_bounds__(256) void norm_rope_kernel(const unsigned short* __restrict__ lin0,
    const unsigned short* __restrict__ lin1, const float* __restrict__ gq,
    const float* __restrict__ gk, const float* __restrict__ freqs, const int* __restrict__ cur,
    unsigned short* __restrict__ qb, unsigned short* __restrict__ kb,
    int S_, int CACHE_, int L_, float qsc){
  const int q = blockIdx.x, t = threadIdx.x;
  const int path = blockIdx.y;
  const unsigned short* lin = path ? lin1 : lin0;
  const float* g = path ? gk : gq;
  unsigned short* out = path ? kb : qb;
  const size_t head_stride = path ? (size_t)L_*HDIM : (size_t)S_*HDIM;
  const int row_off = path ? CACHE_ : 0;
  const float oscale = path ? 1.0f : qsc;
  u16x8 v = *(const u16x8*)(lin + (size_t)q*DIMN + t*8);
  float x[8];
  #pragma unroll
  for (int e=0;e<8;++e) x[e] = bf2f(v[e]);
  float ss = 0.f;
  #pragma unroll
  for (int e=0;e<8;++e) ss += x[e]*x[e];
  for (int m=1;m<64;m<<=1) ss += __shfl_xor(ss, m);
  __shared__ float red[4];
  if ((t & 63) == 0) red[t>>6] = ss;
  __syncthreads();
  const float tot = red[0]+red[1]+red[2]+red[3];
  const float rstd = rsqrtf(tot * (1.0f/2048.0f) + 1e-6f);
  const int n0 = t*8;
  float xr[8];
  #pragma unroll
  for (int e=0;e<8;++e) xr[e] = x[e] * rstd * g[n0+e];
  const int pos = cur[0] + q;
  const int hh = n0 >> 7, d0 = n0 & 127;
  const float* fr = freqs + (size_t)pos * HDIM;
  float o[8];
  #pragma unroll
  for (int p=0;p<4;++p){
    const int j = (d0>>1) + p;
    const float c = fr[j], s = fr[64+j];
    o[2*p]   = xr[2*p]*c - xr[2*p+1]*s;
    o[2*p+1] = xr[2*p+1]*c + xr[2*p]*s;
  }
  u16x8 ov;
  #pragma unroll
  for (int e=0;e<8;++e) ov[e] = f2bf(o[e]*oscale);
  *(u16x8*)(out + (size_t)hh*head_stride + (size_t)(q+row_off)*HDIM + d0) = ov;
}

// ---------------- C[M,N] = A[M,K] * B[N,K]^T + bias, bf16 in fp32 out ----------------
__global__ __launch_bounds__(256,2) void gemm_bt(const unsigned short* __restrict__ A,
    const unsigned short* __restrict__ B, const float* __restrict__ bias,
    float* __restrict__ C, int M, int N, int K){
  __shared__ __align__(16) unsigned short As[2][128*64];
  __shared__ __align__(16) unsigned short Bs[2][128*64];
  const int mb = (M + 127) >> 7;
  const int swz = xcd_swz(blockIdx.x, gridDim.x);
  const int bx = swz / mb, by = swz % mb;
  const int t = threadIdx.x;
  const int w = t >> 6, lane = t & 63, lh = lane >> 4, ll = lane & 15;
  const int wr = w >> 1, wc = w & 1;
  const int m0 = by * 128, n0 = bx * 128;
  const int srow = t >> 3;
  const int scb  = (t & 7) * 16;
  const int swc  = (scb ^ ((srow & 7) << 4)) >> 1;
  int arow[4]; size_t brow[4];
  #pragma unroll
  for (int c=0;c<4;++c){
    int r = m0 + c*32 + srow; if (r >= M) r = M-1;
    arow[c] = r;
    brow[c] = (size_t)(n0 + c*32 + srow);
  }
  const int xsw = (ll & 7) << 4;
  f32x4 acc[4][4] = {};
  const int nk = K >> 6;
  auto stage = [&](int b, int kt){
    const int k0 = kt << 6;
    #pragma unroll
    for (int c=0;c<4;++c){
      gl_lds16(A + (size_t)arow[c]*K + k0 + swc, (char*)As[b] + c*4096 + w*1024);
      gl_lds16(B + brow[c]*K       + k0 + swc, (char*)Bs[b] + c*4096 + w*1024);
    }
  };
  stage(0, 0);
  asm volatile("s_waitcnt vmcnt(0)" ::: "memory");
  __syncthreads();
  int cur = 0;
  for (int kt = 0; kt < nk; ++kt){
    if (kt + 1 < nk) stage(cur ^ 1, kt + 1);
    #pragma unroll
    for (int kk=0;kk<2;++kk){
      const int cb = kk*64 + lh*16;
      bfx8 a[4], b[4];
      #pragma unroll
      for (int i=0;i<4;++i)
        a[i] = *(const bfx8*)((const char*)As[cur] + (wr*64 + i*16 + ll)*128 + (cb ^ xsw));
      #pragma unroll
      for (int j=0;j<4;++j)
        b[j] = *(const bfx8*)((const char*)Bs[cur] + (wc*64 + j*16 + ll)*128 + (cb ^ xsw));
      __builtin_amdgcn_s_setprio(1);
      #pragma unroll
      for (int i=0;i<4;++i)
        #pragma unroll
        for (int j=0;j<4;++j)
          acc[i][j] = MFMA16(a[i], b[j], acc[i][j]);
      __builtin_amdgcn_s_setprio(0);
    }
    asm volatile("s_waitcnt vmcnt(0)" ::: "memory");
    __syncthreads();
    cur ^= 1;
  }
  #pragma unroll
  for (int i=0;i<4;++i){
    #pragma unroll
    for (int j=0;j<4;++j){
      const int col = n0 + wc*64 + j*16 + ll;
      const float bb = bias[col];
      #pragma unroll
      for (int r=0;r<4;++r){
        const int row = m0 + wr*64 + i*16 + lh*4 + r;
        if (row < M) C[(size_t)row*N + col] = acc[i][j][r] + bb;
      }
    }
  }
}

// ---------------- fused QKV gemm (1D grid + XCD swizzle); dbuf; bf16 out ----------------
__global__ __launch_bounds__(256,2) void gemm_qkv(const unsigned short* __restrict__ A,
    const unsigned short* __restrict__ B0, const unsigned short* __restrict__ B1,
    const unsigned short* __restrict__ B2, const float* __restrict__ g0,
    const float* __restrict__ g1, const float* __restrict__ g2,
    unsigned short* __restrict__ C0, unsigned short* __restrict__ C1,
    unsigned short* __restrict__ C2, int M, int N, int K){
  const int mb = (M + 127) >> 7;
  const int nxt = N >> 7;
  const int per = nxt * mb;
  const int swz = xcd_swz(blockIdx.x, gridDim.x);
  const int zz = swz / per;
  const int rem = swz - zz * per;
  const int bx = rem / mb, by = rem % mb;
  const unsigned short* B = (zz==0) ? B0 : (zz==1) ? B1 : B2;
  const float* bias       = (zz==0) ? g0 : (zz==1) ? g1 : g2;
  unsigned short* C       = (zz==0) ? C0 : (zz==1) ? C1 : C2;
  __shared__ __align__(16) unsigned short As[2][128*64];
  __shared__ __align__(16) unsigned short Bs[2][128*64];
  const int t = threadIdx.x;
  const int w = t >> 6, lane = t & 63, lh = lane >> 4, ll = lane & 15;
  const int wr = w >> 1, wc = w & 1;
  const int m0 = by * 128, n0 = bx * 128;
  const int srow = t >> 3;
  const int scb  = (t & 7) * 16;
  const int swc  = (scb ^ ((srow & 7) << 4)) >> 1;
  int arow[4]; size_t brow[4];
  #pragma unroll
  for (int c=0;c<4;++c){
    int r = m0 + c*32 + srow; if (r >= M) r = M-1;
    arow[c] = r;
    brow[c] = (size_t)(n0 + c*32 + srow);
  }
  const int xsw = (ll & 7) << 4;
  f32x4 acc[4][4] = {};
  const int nk = K >> 6;
  auto stage = [&](int b, int kt){
    const int k0 = kt << 6;
    #pragma unroll
    for (int c=0;c<4;++c){
      gl_lds16(A + (size_t)arow[c]*K + k0 + swc, (char*)As[b] + c*4096 + w*1024);
      gl_lds16(B + brow[c]*K       + k0 + swc, (char*)Bs[b] + c*4096 + w*1024);
    }
  };
  stage(0, 0);
  asm volatile("s_waitcnt vmcnt(0)" ::: "memory");
  __syncthreads();
  int cur = 0;
  for (int kt = 0; kt < nk; ++kt){
    if (kt + 1 < nk) stage(cur ^ 1, kt + 1);
    #pragma unroll
    for (int kk=0;kk<2;++kk){
      const int cb = kk*64 + lh*16;
      bfx8 a[4], b[4];
      #pragma unroll
      for (int i=0;i<4;++i)
        a[i] = *(const bfx8*)((const char*)As[cur] + (wr*64 + i*16 + ll)*128 + (cb ^ xsw));
      #pragma unroll
      for (int j=0;j<4;++j)
        b[j] = *(const bfx8*)((const char*)Bs[cur] + (wc*64 + j*16 + ll)*128 + (cb ^ xsw));
      __builtin_amdgcn_s_setprio(1);
      #pragma unroll
      for (int i=0;i<4;++i)
        #pragma unroll
        for (int j=0;j<4;++j)
          acc[i][j] = MFMA16(a[i], b[j], acc[i][j]);
      __builtin_amdgcn_s_setprio(0);
    }
    asm volatile("s_waitcnt vmcnt(0)" ::: "memory");
    __syncthreads();
    cur ^= 1;
  }
  #pragma unroll
  for (int i=0;i<4;++i){
    #pragma unroll
    for (int j=0;j<4;++j){
      const int col = n0 + wc*64 + j*16 + ll;
      const float bb = bias[col];
      #pragma unroll
      for (int r=0;r<4;++r){
        const int row = m0 + wr*64 + i*16 + lh*4 + r;
        if (row < M) C[(size_t)row*N + col] = f2bf(acc[i][j][r] + bb);
      }
    }
  }
}

// ---------------- flash attention: 4 waves, 32x32x16 MFMA, gl_lds dbuf staging --------
__global__ __launch_bounds__(256,2) void attn_kernel(const unsigned short* __restrict__ Q,
    const unsigned short* __restrict__ K, const unsigned short* __restrict__ VT,
    unsigned short* __restrict__ O, float* __restrict__ pacc, float* __restrict__ pml,
    int S_, int L_, int CLn, int nx, int nsplit){
  __shared__ __align__(16) unsigned short Ks[2][64*128];
  __shared__ __align__(16) unsigned short Vs[2][128*64];
  __shared__ __align__(16) unsigned short Ps[4][32*64];
  const int nwg = gridDim.x;
  const int swzid = (blockIdx.x & 7)*(nwg >> 3) + (blockIdx.x >> 3);
  const int xq = swzid % nx;
  const int rest = swzid / nx;
  const int hh = rest % NH;
  const int z  = rest / NH;
  const int q0 = xq * 128;
  const int t = threadIdx.x, w = t >> 6, lane = t & 63;
  const int l31 = lane & 31, h = lane >> 5;
  char* Pw = (char*)Ps[w];
  const int xswp = (l31 & 7) << 4;
  const unsigned short* Qh = Q  + (size_t)hh*S_*HDIM;
  const unsigned short* Kh = K  + (size_t)hh*L_*HDIM;
  const unsigned short* Vh = VT + (size_t)hh*HDIM*L_;
  const int wrow0 = q0 + w*32;
  const int myq = wrow0 + l31;
  bfx8 qf[8];
  {
    int qr = myq; if (qr >= S_) qr = S_ - 1;
    #pragma unroll
    for (int kk=0;kk<8;++kk)
      qf[kk] = *(const bfx8*)(Qh + (size_t)qr*HDIM + kk*16 + h*8);
  }
  f32x16 acc[4] = {};
  float m_st = -1e20f, l_st = 0.f;
  int qlast = q0 + 127; if (qlast >= S_) qlast = S_ - 1;
  const int kend = CLn + qlast + 1;
  const int nt = (kend + 63) >> 6;
  const int tps = (nt + nsplit - 1) / nsplit;
  const int t0 = z * tps;
  int t1 = t0 + tps; if (t1 > nt) t1 = nt;
  const int ksrow = t >> 4;
  const int kswc  = (((t & 15)*16) ^ ((ksrow & 7) << 4)) >> 1;
  const int vsrow = t >> 3;
  const int vswc  = (((t & 7)*16) ^ ((vsrow & 7) << 4)) >> 1;

  auto stage = [&](int b, int ktile){
    const int kv0 = ktile << 6;
    #pragma unroll
    for (int c=0;c<4;++c)
      gl_lds16(Kh + (size_t)(kv0 + c*16 + ksrow)*HDIM + kswc, (char*)Ks[b] + c*4096 + w*1024);
    #pragma unroll
    for (int c=0;c<4;++c)
      gl_lds16(Vh + (size_t)(c*32 + vsrow)*L_ + kv0 + vswc, (char*)Vs[b] + c*4096 + w*1024);
  };

  if (t0 < t1) stage(0, t0);
  asm volatile("s_waitcnt vmcnt(0)" ::: "memory");
  __syncthreads();
  const int krow0 = l31,      koff0 = (krow0 & 7) << 4;
  const int krow1 = 32 + l31, koff1 = (krow1 & 7) << 4;
  int cur = 0;
  for (int kt = t0; kt < t1; ++kt){
    const int kv0 = kt << 6;
    if (kt + 1 < t1) stage(cur ^ 1, kt + 1);
    const char* Kc = (const char*)Ks[cur];
    const char* Vc = (const char*)Vs[cur];
    f32x16 sc0 = {}, sc1 = {};
    __builtin_amdgcn_s_setprio(1);
    #pragma unroll
    for (int kk=0;kk<8;++kk){
      const int cb = kk*32 + h*16;
      bfx8 kf0 = *(const bfx8*)(Kc + krow0*256 + (cb ^ koff0));
      bfx8 kf1 = *(const bfx8*)(Kc + krow1*256 + (cb ^ koff1));
      sc0 = MFMA32(kf0, qf[kk], sc0);
      sc1 = MFMA32(kf1, qf[kk], sc1);
    }
    __builtin_amdgcn_s_setprio(0);
    if (kv0 + 63 > CLn + wrow0){
      const int lim = CLn + myq;
      #pragma unroll
      for (int r=0;r<16;++r){
        const int kl = (r&3) + 8*(r>>2) + 4*h;
        if (kv0 + kl      > lim) sc0[r] = -1e30f;
        if (kv0 + 32 + kl > lim) sc1[r] = -1e30f;
      }
    }
    // row max: v_max3-friendly triples + cross-half
    float mt = sc0[0];
    #pragma unroll
    for (int r=1;r<15;r+=2) mt = fmaxf(fmaxf(sc0[r], sc0[r+1]), mt);
    mt = fmaxf(sc0[15], mt);
    #pragma unroll
    for (int r=0;r<16;r+=2) mt = fmaxf(fmaxf(sc1[r], sc1[r+1]), mt);
    mt = fmaxf(mt, __shfl_xor(mt, 32));
    mt = fmaxf(mt, -1e20f);
    if (!__all(mt - m_st <= 11.54f)){
      const float mn = fmaxf(m_st, mt);
      const float corr = exp2f(m_st - mn);
      m_st = mn;
      l_st *= corr;
      #pragma unroll
      for (int r=0;r<16;++r){
        const int qrow = (r&3) + 8*(r>>2) + 4*h;
        const float ca = __shfl(corr, qrow);
        #pragma unroll
        for (int db=0;db<4;++db) acc[db][r] *= ca;
      }
    }
    float rs = 0.f;
    #pragma unroll
    for (int r=0;r<16;++r){
      const float p0 = exp2f(sc0[r] - m_st);
      const float p1 = exp2f(sc1[r] - m_st);
      sc0[r] = p0; sc1[r] = p1;
      rs += p0 + p1;
    }
    rs += __shfl_xor(rs, 32);
    l_st += rs;
    #pragma unroll
    for (int i=0;i<4;++i){
      bf16x4 p0 = { (__bf16)sc0[4*i], (__bf16)sc0[4*i+1], (__bf16)sc0[4*i+2], (__bf16)sc0[4*i+3] };
      bf16x4 p1 = { (__bf16)sc1[4*i], (__bf16)sc1[4*i+1], (__bf16)sc1[4*i+2], (__bf16)sc1[4*i+3] };
      const int kb0b = (8*i + 4*h) * 2;
      *(bf16x4*)(Pw + l31*128 + (kb0b        ^ xswp)) = p0;
      *(bf16x4*)(Pw + l31*128 + ((64 + kb0b) ^ xswp)) = p1;
    }
    __builtin_amdgcn_s_setprio(1);
    #pragma unroll
    for (int s=0;s<4;++s){
      bfx8 pa = *(const bfx8*)(Pw + l31*128 + ((s*32 + h*16) ^ xswp));
      const int vb = s*32 + h*16;
      #pragma unroll
      for (int db=0;db<4;++db){
        const int vrow = db*32 + l31;
        bfx8 vf = *(const bfx8*)(Vc + vrow*128 + (vb ^ ((vrow & 7) << 4)));
        acc[db] = MFMA32(pa, vf, acc[db]);
      }
    }
    __builtin_amdgcn_s_setprio(0);
    asm volatile("s_waitcnt vmcnt(0)" ::: "memory");
    __syncthreads();
    cur ^= 1;
  }
  if (nsplit == 1){
    const float linv = 1.0f / l_st;
    #pragma unroll
    for (int r=0;r<16;++r){
      const int qrow = (r&3) + 8*(r>>2) + 4*h;
      const float inv = __shfl(linv, qrow);
      const int qr = wrow0 + qrow;
      if (qr < S_){
        #pragma unroll
        for (int db=0;db<4;++db)
          O[(size_t)qr*DIMN + hh*HDIM + db*32 + l31] = f2bf(acc[db][r]*inv);
      }
    }
  } else {
    #pragma unroll
    for (int r=0;r<16;++r){
      const int qrow = (r&3) + 8*(r>>2) + 4*h;
      const int qr = wrow0 + qrow;
      if (qr < S_){
        const size_t rid = ((size_t)z*NH + hh)*S_ + qr;
        float* dst = pacc + rid*128;
        #pragma unroll
        for (int db=0;db<4;++db) dst[db*32 + l31] = acc[db][r];
      }
    }
    if (lane < 32 && myq < S_){
      const size_t rid2 = ((size_t)z*NH + hh)*S_ + myq;
      pml[rid2*2]   = m_st;
      pml[rid2*2+1] = l_st;
    }
  }
}

// ---------------- combine partials -> ob bf16 (exp2 domain m) ----------------
__global__ __launch_bounds__(256) void combine_kernel(const float* __restrict__ pacc,
    const float* __restrict__ pml, unsigned short* __restrict__ ob, int S_, int nsplit){
  const int t = threadIdx.x;
  const int rid = blockIdx.x*2 + (t >> 7);   // hh*S_+q
  if (rid >= S_*NH) return;
  const int d = t & 127;
  const int hh = rid / S_;
  const int q  = rid - hh*S_;
  float M = -1e20f;
  for (int s=0; s<nsplit; ++s)
    M = fmaxf(M, pml[((size_t)s*NH*S_ + rid)*2]);
  float lt = 0.f, o = 0.f;
  for (int s=0; s<nsplit; ++s){
    const float m = pml[((size_t)s*NH*S_ + rid)*2];
    const float l = pml[((size_t)s*NH*S_ + rid)*2 + 1];
    const float wgt = exp2f(m - M);
    lt += l * wgt;
    o  += pacc[((size_t)s*NH*S_ + rid)*128 + d] * wgt;
  }
  if (lt == 0.f) lt = 1.f;
  ob[(size_t)q*DIMN + hh*HDIM + d] = f2bf(o / lt);
}

extern "C" void kernel_launch(void* const* d_in, const int* in_sizes, int n_in,
                              void* d_out, int out_size, void* d_ws, size_t ws_size,
                              hipStream_t stream){
  const float* x       = (const float*)d_in[0];
  const float* freqs   = (const float*)d_in[1];
  const float* k_cache = (const float*)d_in[2];
  const float* v_cache = (const float*)d_in[3];
  const float* Wq = (const float*)d_in[4];
  const float* bq = (const float*)d_in[5];
  const float* Wk = (const float*)d_in[6];
  const float* bk = (const float*)d_in[7];
  const float* Wv = (const float*)d_in[8];
  const float* bv = (const float*)d_in[9];
  const float* Wo = (const float*)d_in[10];
  const float* bo = (const float*)d_in[11];
  const float* gq = (const float*)d_in[12];
  const float* gk = (const float*)d_in[13];
  const int*   cur = (const int*)d_in[14];

  const int S = in_sizes[0] / DIMN;
  const int CACHE_ = in_sizes[2] / DIMN;
  const int L = CACHE_ + S;
  const int CLn = L - S;

  auto al = [](size_t n){ return (n + 255) & ~(size_t)255; };
  char* base = (char*)d_ws;
  size_t off = 0;
  auto take = [&](size_t n){ char* r = base + off; off += al(n); return r; };
  // persistent:
  unsigned short* xb  = (unsigned short*)take((size_t)S*DIMN*2);
  unsigned short* Wob = (unsigned short*)take((size_t)DIMN*DIMN*2);
  unsigned short* qb  = (unsigned short*)take((size_t)NH*S*HDIM*2);
  unsigned short* kb  = (unsigned short*)take((size_t)NH*L*HDIM*2);
  unsigned short* vtb = (unsigned short*)take((size_t)NH*HDIM*L*2);
  unsigned short* ob  = (unsigned short*)take((size_t)S*DIMN*2);
  const size_t ubase = off;
  // union pool A: transients (dead before attn): lin0/1/2 (bf16) + Wq/Wk/Wv (bf16)
  const size_t l_sz = al((size_t)S*DIMN*2);
  const size_t w_sz = al((size_t)DIMN*DIMN*2);
  unsigned short* lin0 = (unsigned short*)(base + ubase);
  unsigned short* lin1 = (unsigned short*)(base + ubase + l_sz);
  unsigned short* lin2 = (unsigned short*)(base + ubase + 2*l_sz);
  unsigned short* Wqb  = (unsigned short*)(base + ubase + 3*l_sz);
  unsigned short* Wkb  = (unsigned short*)(base + ubase + 3*l_sz + w_sz);
  unsigned short* Wvb  = (unsigned short*)(base + ubase + 3*l_sz + 2*w_sz);
  const size_t trans_sz = 3*l_sz + 3*w_sz;
  // union pool B: attention partials
  auto pool_sz = [&](int ns){
    return al((size_t)ns*NH*S*HDIM*4) + al((size_t)ns*NH*S*2*4);
  };
  int nsplit = 1;
  if (ubase + (trans_sz > pool_sz(4) ? trans_sz : pool_sz(4)) <= ws_size) nsplit = 4;
  else if (ubase + (trans_sz > pool_sz(2) ? trans_sz : pool_sz(2)) <= ws_size) nsplit = 2;
  if (ubase + trans_sz > ws_size) return;
  float* pacc = (float*)(base + ubase);
  float* pml  = (float*)(base + ubase + al((size_t)nsplit*NH*S*HDIM*4));

  // merged prep: x/W casts + kcache + v_cache transpose
  const int WB = (DIMN*DIMN/8)/256;
  const int nkb = (CACHE_ + 63) >> 6;
  const int prep_blocks = S + 4*WB + CACHE_ + nkb*4*NH;
  prep_kernel<<<prep_blocks, 256, 0, stream>>>(x, Wq, Wk, Wv, Wo, k_cache, v_cache,
                                               xb, Wqb, Wkb, Wvb, Wob, kb, vtb,
                                               S, CACHE_, L);

  const int mb = (S+127)/128;
  gemm_qkv<<<(DIMN/128)*mb*3, 256, 0, stream>>>(xb, Wqb, Wkb, Wvb, bq, bk, bv,
                                                lin0, lin1, lin2, S, DIMN, DIMN);
  const float qsc = 0.08838834764831845f * 1.4426950408889634f;
  norm_rope_kernel<<<dim3(S,2), 256, 0, stream>>>(lin0, lin1, gq, gk, freqs, cur,
                                                  qb, kb, S, CACHE_, L, qsc);
  vtrans_bf16_kernel<<<dim3((S+63)/64, 4, NH), 256, 0, stream>>>(lin2, vtb, S, CACHE_, L);

  const int nx = (S+127)/128;
  attn_kernel<<<nx*NH*nsplit, 256, 0, stream>>>(qb, kb, vtb, ob,
                                                pacc, pml, S, L, CLn, nx, nsplit);
  if (nsplit > 1)
    combine_kernel<<<(S*NH+1)/2, 256, 0, stream>>>(pacc, pml, ob, S, nsplit);
  gemm_bt<<<(DIMN/128)*mb, 256, 0, stream>>>(ob, Wob, bo, (float*)d_out, S, DIMN, DIMN);
}

// Round 17
// 464.923 us; speedup vs baseline: 1.0858x; 1.0174x over previous
//
#include <hip/hip_runtime.h>

#define DIMN 2048
#define NH 16
#define HDIM 128

typedef __attribute__((ext_vector_type(4))) float f32x4;
typedef __attribute__((ext_vector_type(16))) float f32x16;
typedef __attribute__((ext_vector_type(8))) __bf16 bfx8;
typedef __attribute__((ext_vector_type(4))) __bf16 bf16x4;
typedef __attribute__((ext_vector_type(8))) unsigned short u16x8;

__device__ __forceinline__ unsigned short f2bf(float f){
  unsigned u = __builtin_bit_cast(unsigned, f);
  u += 0x7fffu + ((u >> 16) & 1u);
  return (unsigned short)(u >> 16);
}
__device__ __forceinline__ float bf2f(unsigned short h){
  unsigned u = (unsigned)h << 16;
  return __builtin_bit_cast(float, u);
}

__device__ __forceinline__ void gl_lds16(const void* g, void* l){
  __builtin_amdgcn_global_load_lds((const __attribute__((address_space(1))) void*)g,
                                   (__attribute__((address_space(3))) void*)l, 16, 0, 0);
}

// m204 bijective XCD-chunked remap (works for any nwg)
__device__ __forceinline__ int xcd_swz(int bid, int nwg){
  const int q = nwg >> 3, r = nwg & 7;
  const int xcd = bid & 7, idx = bid >> 3;
  return (xcd < r ? xcd*(q+1) : r*(q+1) + (xcd-r)*q) + idx;
}

#define MFMA16(a,b,c) __builtin_amdgcn_mfma_f32_16x16x32_bf16((a),(b),(c),0,0,0)
#define MFMA32(a,b,c) __builtin_amdgcn_mfma_f32_32x32x16_bf16((a),(b),(c),0,0,0)

// ---------------- merged prep: casts + kcache relayout + v_cache transpose ----------
__global__ __launch_bounds__(256) void prep_kernel(const float* __restrict__ x,
    const float* __restrict__ Wq, const float* __restrict__ Wk, const float* __restrict__ Wv,
    const float* __restrict__ Wo, const float* __restrict__ k_cache,
    const float* __restrict__ v_cache,
    unsigned short* __restrict__ xb, unsigned short* __restrict__ Wqb,
    unsigned short* __restrict__ Wkb, unsigned short* __restrict__ Wvb,
    unsigned short* __restrict__ Wob, unsigned short* __restrict__ kb,
    unsigned short* __restrict__ vtb, int S_, int CACHE_, int L_){
  __shared__ __align__(16) unsigned short tile[32][72];
  const int WB = (DIMN*DIMN/8)/256;   // 2048 blocks per weight
  const int t = threadIdx.x;
  int bid = blockIdx.x;
  if (bid < S_){
    const size_t base = (size_t)bid*DIMN + t*8;
    const float4* p = (const float4*)(x + base);
    float4 a = p[0], b = p[1];
    u16x8 o;
    o[0]=f2bf(a.x); o[1]=f2bf(a.y); o[2]=f2bf(a.z); o[3]=f2bf(a.w);
    o[4]=f2bf(b.x); o[5]=f2bf(b.y); o[6]=f2bf(b.z); o[7]=f2bf(b.w);
    *(u16x8*)(xb + base) = o;
    return;
  }
  bid -= S_;
  if (bid < 4*WB){
    const int wsel = bid / WB;
    const int lb   = bid - wsel*WB;
    const float* in = (wsel==0) ? Wq : (wsel==1) ? Wk : (wsel==2) ? Wv : Wo;
    unsigned short* out = (wsel==0) ? Wqb : (wsel==1) ? Wkb : (wsel==2) ? Wvb : Wob;
    const size_t base = ((size_t)lb*256 + t)*8;
    const float4* p = (const float4*)(in + base);
    float4 a = p[0], b = p[1];
    u16x8 o;
    o[0]=f2bf(a.x); o[1]=f2bf(a.y); o[2]=f2bf(a.z); o[3]=f2bf(a.w);
    o[4]=f2bf(b.x); o[5]=f2bf(b.y); o[6]=f2bf(b.z); o[7]=f2bf(b.w);
    *(u16x8*)(out + base) = o;
    return;
  }
  bid -= 4*WB;
  if (bid < CACHE_){
    const size_t idx = ((size_t)bid*256 + t)*8;
    const int k   = (int)(idx >> 11);
    const int rem = (int)(idx & 2047);
    const int hh  = rem >> 7, d = rem & 127;
    const float4* p = (const float4*)(k_cache + idx);
    float4 a = p[0], b = p[1];
    u16x8 o;
    o[0]=f2bf(a.x); o[1]=f2bf(a.y); o[2]=f2bf(a.z); o[3]=f2bf(a.w);
    o[4]=f2bf(b.x); o[5]=f2bf(b.y); o[6]=f2bf(b.z); o[7]=f2bf(b.w);
    *(u16x8*)(kb + (size_t)hh*L_*HDIM + (size_t)k*HDIM + d) = o;
    return;
  }
  bid -= CACHE_;
  {
    const int nkb = (CACHE_ + 63) >> 6;
    const int kbi = bid % nkb;
    const int rest = bid / nkb;
    const int dbi = rest & 3;
    const int hh  = rest >> 2;
    const int kb0 = kbi * 64, db0 = dbi * 32;
    const int kk = t >> 2, dd = (t & 3) * 8;
    const int k = kb0 + kk;
    if (k < CACHE_){
      const float* p = v_cache + (size_t)k*DIMN + hh*HDIM + db0 + dd;
      float4 a = ((const float4*)p)[0], b = ((const float4*)p)[1];
      tile[dd+0][kk] = f2bf(a.x); tile[dd+1][kk] = f2bf(a.y);
      tile[dd+2][kk] = f2bf(a.z); tile[dd+3][kk] = f2bf(a.w);
      tile[dd+4][kk] = f2bf(b.x); tile[dd+5][kk] = f2bf(b.y);
      tile[dd+6][kk] = f2bf(b.z); tile[dd+7][kk] = f2bf(b.w);
    }
    __syncthreads();
    const int d = t >> 3, k0 = (t & 7) * 8;
    unsigned short* dst = vtb + (size_t)hh*HDIM*L_ + (size_t)(db0+d)*L_ + kb0 + k0;
    if (kb0 + k0 + 8 <= CACHE_){
      *(u16x8*)dst = *(const u16x8*)&tile[d][k0];
    } else {
      #pragma unroll
      for (int e=0;e<8;++e) if (kb0 + k0 + e < CACHE_) dst[e] = tile[d][k0+e];
    }
  }
}

// ---------------- merged post-projection: rmsnorm+RoPE (Q/K) + V transpose ----------
// blocks [0,S): Q path; [S,2S): K path; [2S, 2S+nvb): vtrans of lin2 (projected V).
__global__ __launch_bounds__(256) void postproj_kernel(const unsigned short* __restrict__ lin0,
    const unsigned short* __restrict__ lin1, const unsigned short* __restrict__ lin2,
    const float* __restrict__ gq, const float* __restrict__ gk,
    const float* __restrict__ freqs, const int* __restrict__ cur,
    unsigned short* __restrict__ qb, unsigned short* __restrict__ kb,
    unsigned short* __restrict__ vtb,
    int S_, int CACHE_, int L_, float qsc){
  __shared__ __align__(16) unsigned short tile[32][72];
  __shared__ float red[4];
  const int t = threadIdx.x;
  int bid = blockIdx.x;
  if (bid < 2*S_){
    // ---- norm + RoPE ----
    const int path = (bid >= S_) ? 1 : 0;
    const int q = bid - path*S_;
    const unsigned short* lin = path ? lin1 : lin0;
    const float* g = path ? gk : gq;
    unsigned short* out = path ? kb : qb;
    const size_t head_stride = path ? (size_t)L_*HDIM : (size_t)S_*HDIM;
    const int row_off = path ? CACHE_ : 0;
    const float oscale = path ? 1.0f : qsc;
    u16x8 v = *(const u16x8*)(lin + (size_t)q*DIMN + t*8);
    float x[8];
    #pragma unroll
    for (int e=0;e<8;++e) x[e] = bf2f(v[e]);
    float ss = 0.f;
    #pragma unroll
    for (int e=0;e<8;++e) ss += x[e]*x[e];
    for (int m=1;m<64;m<<=1) ss += __shfl_xor(ss, m);
    if ((t & 63) == 0) red[t>>6] = ss;
    __syncthreads();
    const float tot = red[0]+red[1]+red[2]+red[3];
    const float rstd = rsqrtf(tot * (1.0f/2048.0f) + 1e-6f);
    const int n0 = t*8;
    float xr[8];
    #pragma unroll
    for (int e=0;e<8;++e) xr[e] = x[e] * rstd * g[n0+e];
    const int pos = cur[0] + q;
    const int hh = n0 >> 7, d0 = n0 & 127;
    const float* fr = freqs + (size_t)pos * HDIM;
    float o[8];
    #pragma unroll
    for (int p=0;p<4;++p){
      const int j = (d0>>1) + p;
      const float c = fr[j], s = fr[64+j];
      o[2*p]   = xr[2*p]*c - xr[2*p+1]*s;
      o[2*p+1] = xr[2*p+1]*c + xr[2*p]*s;
    }
    u16x8 ov;
    #pragma unroll
    for (int e=0;e<8;++e) ov[e] = f2bf(o[e]*oscale);
    *(u16x8*)(out + (size_t)hh*head_stride + (size_t)(q+row_off)*HDIM + d0) = ov;
    return;
  }
  bid -= 2*S_;
  {
    // ---- vtrans of projected V (bf16): lin2[S][DIMN] -> vtb[h][d][CACHE_+k] ----
    const int nkb = (S_ + 63) >> 6;
    const int kbi = bid % nkb;
    const int rest = bid / nkb;
    const int dbi = rest & 3;
    const int hh  = rest >> 2;
    const int kb0 = kbi * 64, db0 = dbi * 32;
    const int kk = t >> 2, dd = (t & 3) * 8;
    const int k = kb0 + kk;
    if (k < S_){
      u16x8 a = *(const u16x8*)(lin2 + (size_t)k*DIMN + hh*HDIM + db0 + dd);
      #pragma unroll
      for (int e=0;e<8;++e) tile[dd+e][kk] = a[e];
    }
    __syncthreads();
    const int d = t >> 3, k0 = (t & 7) * 8;
    unsigned short* dst = vtb + (size_t)hh*HDIM*L_ + (size_t)(db0+d)*L_ + CACHE_ + kb0 + k0;
    if (kb0 + k0 + 8 <= S_){
      *(u16x8*)dst = *(const u16x8*)&tile[d][k0];
    } else {
      #pragma unroll
      for (int e=0;e<8;++e) if (kb0 + k0 + e < S_) dst[e] = tile[d][k0+e];
    }
  }
}

// ---------------- C[M,N] = A[M,K] * B[N,K]^T + bias, bf16 in fp32 out ----------------
__global__ __launch_bounds__(256,2) void gemm_bt(const unsigned short* __restrict__ A,
    const unsigned short* __restrict__ B, const float* __restrict__ bias,
    float* __restrict__ C, int M, int N, int K){
  __shared__ __align__(16) unsigned short As[2][128*64];
  __shared__ __align__(16) unsigned short Bs[2][128*64];
  const int mb = (M + 127) >> 7;
  const int swz = xcd_swz(blockIdx.x, gridDim.x);
  const int bx = swz / mb, by = swz % mb;
  const int t = threadIdx.x;
  const int w = t >> 6, lane = t & 63, lh = lane >> 4, ll = lane & 15;
  const int wr = w >> 1, wc = w & 1;
  const int m0 = by * 128, n0 = bx * 128;
  const int srow = t >> 3;
  const int scb  = (t & 7) * 16;
  const int swc  = (scb ^ ((srow & 7) << 4)) >> 1;
  int arow[4]; size_t brow[4];
  #pragma unroll
  for (int c=0;c<4;++c){
    int r = m0 + c*32 + srow; if (r >= M) r = M-1;
    arow[c] = r;
    brow[c] = (size_t)(n0 + c*32 + srow);
  }
  const int xsw = (ll & 7) << 4;
  f32x4 acc[4][4] = {};
  const int nk = K >> 6;
  auto stage = [&](int b, int kt){
    const int k0 = kt << 6;
    #pragma unroll
    for (int c=0;c<4;++c){
      gl_lds16(A + (size_t)arow[c]*K + k0 + swc, (char*)As[b] + c*4096 + w*1024);
      gl_lds16(B + brow[c]*K       + k0 + swc, (char*)Bs[b] + c*4096 + w*1024);
    }
  };
  stage(0, 0);
  asm volatile("s_waitcnt vmcnt(0)" ::: "memory");
  __syncthreads();
  int cur = 0;
  for (int kt = 0; kt < nk; ++kt){
    if (kt + 1 < nk) stage(cur ^ 1, kt + 1);
    #pragma unroll
    for (int kk=0;kk<2;++kk){
      const int cb = kk*64 + lh*16;
      bfx8 a[4], b[4];
      #pragma unroll
      for (int i=0;i<4;++i)
        a[i] = *(const bfx8*)((const char*)As[cur] + (wr*64 + i*16 + ll)*128 + (cb ^ xsw));
      #pragma unroll
      for (int j=0;j<4;++j)
        b[j] = *(const bfx8*)((const char*)Bs[cur] + (wc*64 + j*16 + ll)*128 + (cb ^ xsw));
      __builtin_amdgcn_s_setprio(1);
      #pragma unroll
      for (int i=0;i<4;++i)
        #pragma unroll
        for (int j=0;j<4;++j)
          acc[i][j] = MFMA16(a[i], b[j], acc[i][j]);
      __builtin_amdgcn_s_setprio(0);
    }
    asm volatile("s_waitcnt vmcnt(0)" ::: "memory");
    __syncthreads();
    cur ^= 1;
  }
  #pragma unroll
  for (int i=0;i<4;++i){
    #pragma unroll
    for (int j=0;j<4;++j){
      const int col = n0 + wc*64 + j*16 + ll;
      const float bb = bias[col];
      #pragma unroll
      for (int r=0;r<4;++r){
        const int row = m0 + wr*64 + i*16 + lh*4 + r;
        if (row < M) C[(size_t)row*N + col] = acc[i][j][r] + bb;
      }
    }
  }
}

// ---------------- fused QKV gemm (1D grid + XCD swizzle); dbuf; bf16 out ----------------
__global__ __launch_bounds__(256,2) void gemm_qkv(const unsigned short* __restrict__ A,
    const unsigned short* __restrict__ B0, const unsigned short* __restrict__ B1,
    const unsigned short* __restrict__ B2, const float* __restrict__ g0,
    const float* __restrict__ g1, const float* __restrict__ g2,
    unsigned short* __restrict__ C0, unsigned short* __restrict__ C1,
    unsigned short* __restrict__ C2, int M, int N, int K){
  const int mb = (M + 127) >> 7;
  const int nxt = N >> 7;
  const int per = nxt * mb;
  const int swz = xcd_swz(blockIdx.x, gridDim.x);
  const int zz = swz / per;
  const int rem = swz - zz * per;
  const int bx = rem / mb, by = rem % mb;
  const unsigned short* B = (zz==0) ? B0 : (zz==1) ? B1 : B2;
  const float* bias       = (zz==0) ? g0 : (zz==1) ? g1 : g2;
  unsigned short* C       = (zz==0) ? C0 : (zz==1) ? C1 : C2;
  __shared__ __align__(16) unsigned short As[2][128*64];
  __shared__ __align__(16) unsigned short Bs[2][128*64];
  const int t = threadIdx.x;
  const int w = t >> 6, lane = t & 63, lh = lane >> 4, ll = lane & 15;
  const int wr = w >> 1, wc = w & 1;
  const int m0 = by * 128, n0 = bx * 128;
  const int srow = t >> 3;
  const int scb  = (t & 7) * 16;
  const int swc  = (scb ^ ((srow & 7) << 4)) >> 1;
  int arow[4]; size_t brow[4];
  #pragma unroll
  for (int c=0;c<4;++c){
    int r = m0 + c*32 + srow; if (r >= M) r = M-1;
    arow[c] = r;
    brow[c] = (size_t)(n0 + c*32 + srow);
  }
  const int xsw = (ll & 7) << 4;
  f32x4 acc[4][4] = {};
  const int nk = K >> 6;
  auto stage = [&](int b, int kt){
    const int k0 = kt << 6;
    #pragma unroll
    for (int c=0;c<4;++c){
      gl_lds16(A + (size_t)arow[c]*K + k0 + swc, (char*)As[b] + c*4096 + w*1024);
      gl_lds16(B + brow[c]*K       + k0 + swc, (char*)Bs[b] + c*4096 + w*1024);
    }
  };
  stage(0, 0);
  asm volatile("s_waitcnt vmcnt(0)" ::: "memory");
  __syncthreads();
  int cur = 0;
  for (int kt = 0; kt < nk; ++kt){
    if (kt + 1 < nk) stage(cur ^ 1, kt + 1);
    #pragma unroll
    for (int kk=0;kk<2;++kk){
      const int cb = kk*64 + lh*16;
      bfx8 a[4], b[4];
      #pragma unroll
      for (int i=0;i<4;++i)
        a[i] = *(const bfx8*)((const char*)As[cur] + (wr*64 + i*16 + ll)*128 + (cb ^ xsw));
      #pragma unroll
      for (int j=0;j<4;++j)
        b[j] = *(const bfx8*)((const char*)Bs[cur] + (wc*64 + j*16 + ll)*128 + (cb ^ xsw));
      __builtin_amdgcn_s_setprio(1);
      #pragma unroll
      for (int i=0;i<4;++i)
        #pragma unroll
        for (int j=0;j<4;++j)
          acc[i][j] = MFMA16(a[i], b[j], acc[i][j]);
      __builtin_amdgcn_s_setprio(0);
    }
    asm volatile("s_waitcnt vmcnt(0)" ::: "memory");
    __syncthreads();
    cur ^= 1;
  }
  #pragma unroll
  for (int i=0;i<4;++i){
    #pragma unroll
    for (int j=0;j<4;++j){
      const int col = n0 + wc*64 + j*16 + ll;
      const float bb = bias[col];
      #pragma unroll
      for (int r=0;r<4;++r){
        const int row = m0 + wr*64 + i*16 + lh*4 + r;
        if (row < M) C[(size_t)row*N + col] = f2bf(acc[i][j][r] + bb);
      }
    }
  }
}

// ---------------- flash attention: 4 waves, 32x32x16 MFMA, gl_lds dbuf staging --------
__global__ __launch_bounds__(256,2) void attn_kernel(const unsigned short* __restrict__ Q,
    const unsigned short* __restrict__ K, const unsigned short* __restrict__ VT,
    unsigned short* __restrict__ O, float* __restrict__ pacc, float* __restrict__ pml,
    int S_, int L_, int CLn, int nx, int nsplit){
  __shared__ __align__(16) unsigned short Ks[2][64*128];
  __shared__ __align__(16) unsigned short Vs[2][128*64];
  __shared__ __align__(16) unsigned short Ps[4][32*64];
  const int nwg = gridDim.x;
  const int swzid = (blockIdx.x & 7)*(nwg >> 3) + (blockIdx.x >> 3);
  const int xq = swzid % nx;
  const int rest = swzid / nx;
  const int hh = rest % NH;
  const int z  = rest / NH;
  const int q0 = xq * 128;
  const int t = threadIdx.x, w = t >> 6, lane = t & 63;
  const int l31 = lane & 31, h = lane >> 5;
  char* Pw = (char*)Ps[w];
  const int xswp = (l31 & 7) << 4;
  const unsigned short* Qh = Q  + (size_t)hh*S_*HDIM;
  const unsigned short* Kh = K  + (size_t)hh*L_*HDIM;
  const unsigned short* Vh = VT + (size_t)hh*HDIM*L_;
  const int wrow0 = q0 + w*32;
  const int myq = wrow0 + l31;
  bfx8 qf[8];
  {
    int qr = myq; if (qr >= S_) qr = S_ - 1;
    #pragma unroll
    for (int kk=0;kk<8;++kk)
      qf[kk] = *(const bfx8*)(Qh + (size_t)qr*HDIM + kk*16 + h*8);
  }
  f32x16 acc[4] = {};
  float m_st = -1e20f, l_st = 0.f;
  int qlast = q0 + 127; if (qlast >= S_) qlast = S_ - 1;
  const int kend = CLn + qlast + 1;
  const int nt = (kend + 63) >> 6;
  const int tps = (nt + nsplit - 1) / nsplit;
  const int t0 = z * tps;
  int t1 = t0 + tps; if (t1 > nt) t1 = nt;
  const int ksrow = t >> 4;
  const int kswc  = (((t & 15)*16) ^ ((ksrow & 7) << 4)) >> 1;
  const int vsrow = t >> 3;
  const int vswc  = (((t & 7)*16) ^ ((vsrow & 7) << 4)) >> 1;

  auto stage = [&](int b, int ktile){
    const int kv0 = ktile << 6;
    #pragma unroll
    for (int c=0;c<4;++c)
      gl_lds16(Kh + (size_t)(kv0 + c*16 + ksrow)*HDIM + kswc, (char*)Ks[b] + c*4096 + w*1024);
    #pragma unroll
    for (int c=0;c<4;++c)
      gl_lds16(Vh + (size_t)(c*32 + vsrow)*L_ + kv0 + vswc, (char*)Vs[b] + c*4096 + w*1024);
  };

  if (t0 < t1) stage(0, t0);
  asm volatile("s_waitcnt vmcnt(0)" ::: "memory");
  __syncthreads();
  const int krow0 = l31,      koff0 = (krow0 & 7) << 4;
  const int krow1 = 32 + l31, koff1 = (krow1 & 7) << 4;
  int cur = 0;
  for (int kt = t0; kt < t1; ++kt){
    const int kv0 = kt << 6;
    if (kt + 1 < t1) stage(cur ^ 1, kt + 1);
    const char* Kc = (const char*)Ks[cur];
    const char* Vc = (const char*)Vs[cur];
    f32x16 sc0 = {}, sc1 = {};
    __builtin_amdgcn_s_setprio(1);
    #pragma unroll
    for (int kk=0;kk<8;++kk){
      const int cb = kk*32 + h*16;
      bfx8 kf0 = *(const bfx8*)(Kc + krow0*256 + (cb ^ koff0));
      bfx8 kf1 = *(const bfx8*)(Kc + krow1*256 + (cb ^ koff1));
      sc0 = MFMA32(kf0, qf[kk], sc0);
      sc1 = MFMA32(kf1, qf[kk], sc1);
    }
    __builtin_amdgcn_s_setprio(0);
    if (kv0 + 63 > CLn + wrow0){
      const int lim = CLn + myq;
      #pragma unroll
      for (int r=0;r<16;++r){
        const int kl = (r&3) + 8*(r>>2) + 4*h;
        if (kv0 + kl      > lim) sc0[r] = -1e30f;
        if (kv0 + 32 + kl > lim) sc1[r] = -1e30f;
      }
    }
    // row max: v_max3-friendly triples + cross-half
    float mt = sc0[0];
    #pragma unroll
    for (int r=1;r<15;r+=2) mt = fmaxf(fmaxf(sc0[r], sc0[r+1]), mt);
    mt = fmaxf(sc0[15], mt);
    #pragma unroll
    for (int r=0;r<16;r+=2) mt = fmaxf(fmaxf(sc1[r], sc1[r+1]), mt);
    mt = fmaxf(mt, __shfl_xor(mt, 32));
    mt = fmaxf(mt, -1e20f);
    if (!__all(mt - m_st <= 11.54f)){
      const float mn = fmaxf(m_st, mt);
      const float corr = exp2f(m_st - mn);
      m_st = mn;
      l_st *= corr;
      #pragma unroll
      for (int r=0;r<16;++r){
        const int qrow = (r&3) + 8*(r>>2) + 4*h;
        const float ca = __shfl(corr, qrow);
        #pragma unroll
        for (int db=0;db<4;++db) acc[db][r] *= ca;
      }
    }
    float rs = 0.f;
    #pragma unroll
    for (int r=0;r<16;++r){
      const float p0 = exp2f(sc0[r] - m_st);
      const float p1 = exp2f(sc1[r] - m_st);
      sc0[r] = p0; sc1[r] = p1;
      rs += p0 + p1;
    }
    rs += __shfl_xor(rs, 32);
    l_st += rs;
    #pragma unroll
    for (int i=0;i<4;++i){
      bf16x4 p0 = { (__bf16)sc0[4*i], (__bf16)sc0[4*i+1], (__bf16)sc0[4*i+2], (__bf16)sc0[4*i+3] };
      bf16x4 p1 = { (__bf16)sc1[4*i], (__bf16)sc1[4*i+1], (__bf16)sc1[4*i+2], (__bf16)sc1[4*i+3] };
      const int kb0b = (8*i + 4*h) * 2;
      *(bf16x4*)(Pw + l31*128 + (kb0b        ^ xswp)) = p0;
      *(bf16x4*)(Pw + l31*128 + ((64 + kb0b) ^ xswp)) = p1;
    }
    __builtin_amdgcn_s_setprio(1);
    #pragma unroll
    for (int s=0;s<4;++s){
      bfx8 pa = *(const bfx8*)(Pw + l31*128 + ((s*32 + h*16) ^ xswp));
      const int vb = s*32 + h*16;
      #pragma unroll
      for (int db=0;db<4;++db){
        const int vrow = db*32 + l31;
        bfx8 vf = *(const bfx8*)(Vc + vrow*128 + (vb ^ ((vrow & 7) << 4)));
        acc[db] = MFMA32(pa, vf, acc[db]);
      }
    }
    __builtin_amdgcn_s_setprio(0);
    asm volatile("s_waitcnt vmcnt(0)" ::: "memory");
    __syncthreads();
    cur ^= 1;
  }
  if (nsplit == 1){
    const float linv = 1.0f / l_st;
    #pragma unroll
    for (int r=0;r<16;++r){
      const int qrow = (r&3) + 8*(r>>2) + 4*h;
      const float inv = __shfl(linv, qrow);
      const int qr = wrow0 + qrow;
      if (qr < S_){
        #pragma unroll
        for (int db=0;db<4;++db)
          O[(size_t)qr*DIMN + hh*HDIM + db*32 + l31] = f2bf(acc[db][r]*inv);
      }
    }
  } else {
    #pragma unroll
    for (int r=0;r<16;++r){
      const int qrow = (r&3) + 8*(r>>2) + 4*h;
      const int qr = wrow0 + qrow;
      if (qr < S_){
        const size_t rid = ((size_t)z*NH + hh)*S_ + qr;
        float* dst = pacc + rid*128;
        #pragma unroll
        for (int db=0;db<4;++db) dst[db*32 + l31] = acc[db][r];
      }
    }
    if (lane < 32 && myq < S_){
      const size_t rid2 = ((size_t)z*NH + hh)*S_ + myq;
      pml[rid2*2]   = m_st;
      pml[rid2*2+1] = l_st;
    }
  }
}

// ---------------- combine partials -> ob bf16 (exp2 domain m) ----------------
__global__ __launch_bounds__(256) void combine_kernel(const float* __restrict__ pacc,
    const float* __restrict__ pml, unsigned short* __restrict__ ob, int S_, int nsplit){
  const int t = threadIdx.x;
  const int rid = blockIdx.x*2 + (t >> 7);   // hh*S_+q
  if (rid >= S_*NH) return;
  const int d = t & 127;
  const int hh = rid / S_;
  const int q  = rid - hh*S_;
  float M = -1e20f;
  for (int s=0; s<nsplit; ++s)
    M = fmaxf(M, pml[((size_t)s*NH*S_ + rid)*2]);
  float lt = 0.f, o = 0.f;
  for (int s=0; s<nsplit; ++s){
    const float m = pml[((size_t)s*NH*S_ + rid)*2];
    const float l = pml[((size_t)s*NH*S_ + rid)*2 + 1];
    const float wgt = exp2f(m - M);
    lt += l * wgt;
    o  += pacc[((size_t)s*NH*S_ + rid)*128 + d] * wgt;
  }
  if (lt == 0.f) lt = 1.f;
  ob[(size_t)q*DIMN + hh*HDIM + d] = f2bf(o / lt);
}

extern "C" void kernel_launch(void* const* d_in, const int* in_sizes, int n_in,
                              void* d_out, int out_size, void* d_ws, size_t ws_size,
                              hipStream_t stream){
  const float* x       = (const float*)d_in[0];
  const float* freqs   = (const float*)d_in[1];
  const float* k_cache = (const float*)d_in[2];
  const float* v_cache = (const float*)d_in[3];
  const float* Wq = (const float*)d_in[4];
  const float* bq = (const float*)d_in[5];
  const float* Wk = (const float*)d_in[6];
  const float* bk = (const float*)d_in[7];
  const float* Wv = (const float*)d_in[8];
  const float* bv = (const float*)d_in[9];
  const float* Wo = (const float*)d_in[10];
  const float* bo = (const float*)d_in[11];
  const float* gq = (const float*)d_in[12];
  const float* gk = (const float*)d_in[13];
  const int*   cur = (const int*)d_in[14];

  const int S = in_sizes[0] / DIMN;
  const int CACHE_ = in_sizes[2] / DIMN;
  const int L = CACHE_ + S;
  const int CLn = L - S;

  auto al = [](size_t n){ return (n + 255) & ~(size_t)255; };
  char* base = (char*)d_ws;
  size_t off = 0;
  auto take = [&](size_t n){ char* r = base + off; off += al(n); return r; };
  // persistent:
  unsigned short* xb  = (unsigned short*)take((size_t)S*DIMN*2);
  unsigned short* Wob = (unsigned short*)take((size_t)DIMN*DIMN*2);
  unsigned short* qb  = (unsigned short*)take((size_t)NH*S*HDIM*2);
  unsigned short* kb  = (unsigned short*)take((size_t)NH*L*HDIM*2);
  unsigned short* vtb = (unsigned short*)take((size_t)NH*HDIM*L*2);
  unsigned short* ob  = (unsigned short*)take((size_t)S*DIMN*2);
  const size_t ubase = off;
  // union pool A: transients (dead before attn): lin0/1/2 (bf16) + Wq/Wk/Wv (bf16)
  const size_t l_sz = al((size_t)S*DIMN*2);
  const size_t w_sz = al((size_t)DIMN*DIMN*2);
  unsigned short* lin0 = (unsigned short*)(base + ubase);
  unsigned short* lin1 = (unsigned short*)(base + ubase + l_sz);
  unsigned short* lin2 = (unsigned short*)(base + ubase + 2*l_sz);
  unsigned short* Wqb  = (unsigned short*)(base + ubase + 3*l_sz);
  unsigned short* Wkb  = (unsigned short*)(base + ubase + 3*l_sz + w_sz);
  unsigned short* Wvb  = (unsigned short*)(base + ubase + 3*l_sz + 2*w_sz);
  const size_t trans_sz = 3*l_sz + 3*w_sz;
  // union pool B: attention partials
  auto pool_sz = [&](int ns){
    return al((size_t)ns*NH*S*HDIM*4) + al((size_t)ns*NH*S*2*4);
  };
  int nsplit = 1;
  if (ubase + (trans_sz > pool_sz(4) ? trans_sz : pool_sz(4)) <= ws_size) nsplit = 4;
  else if (ubase + (trans_sz > pool_sz(2) ? trans_sz : pool_sz(2)) <= ws_size) nsplit = 2;
  if (ubase + trans_sz > ws_size) return;
  float* pacc = (float*)(base + ubase);
  float* pml  = (float*)(base + ubase + al((size_t)nsplit*NH*S*HDIM*4));

  // merged prep: x/W casts + kcache + v_cache transpose
  const int WB = (DIMN*DIMN/8)/256;
  const int nkb = (CACHE_ + 63) >> 6;
  const int prep_blocks = S + 4*WB + CACHE_ + nkb*4*NH;
  prep_kernel<<<prep_blocks, 256, 0, stream>>>(x, Wq, Wk, Wv, Wo, k_cache, v_cache,
                                               xb, Wqb, Wkb, Wvb, Wob, kb, vtb,
                                               S, CACHE_, L);

  const int mb = (S+127)/128;
  gemm_qkv<<<(DIMN/128)*mb*3, 256, 0, stream>>>(xb, Wqb, Wkb, Wvb, bq, bk, bv,
                                                lin0, lin1, lin2, S, DIMN, DIMN);
  // merged post-projection: Q/K norm+RoPE + V transpose in one dispatch
  const float qsc = 0.08838834764831845f * 1.4426950408889634f;
  const int nkb2 = (S + 63) >> 6;
  const int pp_blocks = 2*S + nkb2*4*NH;
  postproj_kernel<<<pp_blocks, 256, 0, stream>>>(lin0, lin1, lin2, gq, gk, freqs, cur,
                                                 qb, kb, vtb, S, CACHE_, L, qsc);

  const int nx = (S+127)/128;
  attn_kernel<<<nx*NH*nsplit, 256, 0, stream>>>(qb, kb, vtb, ob,
                                                pacc, pml, S, L, CLn, nx, nsplit);
  if (nsplit > 1)
    combine_kernel<<<(S*NH+1)/2, 256, 0, stream>>>(pacc, pml, ob, S, nsplit);
  gemm_bt<<<(DIMN/128)*mb, 256, 0, stream>>>(ob, Wob, bo, (float*)d_out, S, DIMN, DIMN);
}

// Round 19
// 463.678 us; speedup vs baseline: 1.0887x; 1.0027x over previous
//
#include <hip/hip_runtime.h>

#define DIMN 2048
#define NH 16
#define HDIM 128

typedef __attribute__((ext_vector_type(4))) float f32x4;
typedef __attribute__((ext_vector_type(16))) float f32x16;
typedef __attribute__((ext_vector_type(8))) __bf16 bfx8;
typedef __attribute__((ext_vector_type(4))) __bf16 bf16x4;
typedef __attribute__((ext_vector_type(8))) unsigned short u16x8;

__device__ __forceinline__ unsigned short f2bf(float f){
  unsigned u = __builtin_bit_cast(unsigned, f);
  u += 0x7fffu + ((u >> 16) & 1u);
  return (unsigned short)(u >> 16);
}
__device__ __forceinline__ float bf2f(unsigned short h){
  unsigned u = (unsigned)h << 16;
  return __builtin_bit_cast(float, u);
}

__device__ __forceinline__ void gl_lds16(const void* g, void* l){
  __builtin_amdgcn_global_load_lds((const __attribute__((address_space(1))) void*)g,
                                   (__attribute__((address_space(3))) void*)l, 16, 0, 0);
}

// m204 bijective XCD-chunked remap (works for any nwg)
__device__ __forceinline__ int xcd_swz(int bid, int nwg){
  const int q = nwg >> 3, r = nwg & 7;
  const int xcd = bid & 7, idx = bid >> 3;
  return (xcd < r ? xcd*(q+1) : r*(q+1) + (xcd-r)*q) + idx;
}

#define MFMA16(a,b,c) __builtin_amdgcn_mfma_f32_16x16x32_bf16((a),(b),(c),0,0,0)
#define MFMA32(a,b,c) __builtin_amdgcn_mfma_f32_32x32x16_bf16((a),(b),(c),0,0,0)

// ---------------- merged prep: casts + kcache relayout + v_cache transpose ----------
__global__ __launch_bounds__(256) void prep_kernel(const float* __restrict__ x,
    const float* __restrict__ Wq, const float* __restrict__ Wk, const float* __restrict__ Wv,
    const float* __restrict__ Wo, const float* __restrict__ k_cache,
    const float* __restrict__ v_cache,
    unsigned short* __restrict__ xb, unsigned short* __restrict__ Wqb,
    unsigned short* __restrict__ Wkb, unsigned short* __restrict__ Wvb,
    unsigned short* __restrict__ Wob, unsigned short* __restrict__ kb,
    unsigned short* __restrict__ vtb, int S_, int CACHE_, int L_){
  __shared__ __align__(16) unsigned short tile[32][72];
  const int WB = (DIMN*DIMN/8)/256;
  const int t = threadIdx.x;
  int bid = blockIdx.x;
  if (bid < S_){
    const size_t base = (size_t)bid*DIMN + t*8;
    const float4* p = (const float4*)(x + base);
    float4 a = p[0], b = p[1];
    u16x8 o;
    o[0]=f2bf(a.x); o[1]=f2bf(a.y); o[2]=f2bf(a.z); o[3]=f2bf(a.w);
    o[4]=f2bf(b.x); o[5]=f2bf(b.y); o[6]=f2bf(b.z); o[7]=f2bf(b.w);
    *(u16x8*)(xb + base) = o;
    return;
  }
  bid -= S_;
  if (bid < 4*WB){
    const int wsel = bid / WB;
    const int lb   = bid - wsel*WB;
    const float* in = (wsel==0) ? Wq : (wsel==1) ? Wk : (wsel==2) ? Wv : Wo;
    unsigned short* out = (wsel==0) ? Wqb : (wsel==1) ? Wkb : (wsel==2) ? Wvb : Wob;
    const size_t base = ((size_t)lb*256 + t)*8;
    const float4* p = (const float4*)(in + base);
    float4 a = p[0], b = p[1];
    u16x8 o;
    o[0]=f2bf(a.x); o[1]=f2bf(a.y); o[2]=f2bf(a.z); o[3]=f2bf(a.w);
    o[4]=f2bf(b.x); o[5]=f2bf(b.y); o[6]=f2bf(b.z); o[7]=f2bf(b.w);
    *(u16x8*)(out + base) = o;
    return;
  }
  bid -= 4*WB;
  if (bid < CACHE_){
    const size_t idx = ((size_t)bid*256 + t)*8;
    const int k   = (int)(idx >> 11);
    const int rem = (int)(idx & 2047);
    const int hh  = rem >> 7, d = rem & 127;
    const float4* p = (const float4*)(k_cache + idx);
    float4 a = p[0], b = p[1];
    u16x8 o;
    o[0]=f2bf(a.x); o[1]=f2bf(a.y); o[2]=f2bf(a.z); o[3]=f2bf(a.w);
    o[4]=f2bf(b.x); o[5]=f2bf(b.y); o[6]=f2bf(b.z); o[7]=f2bf(b.w);
    *(u16x8*)(kb + (size_t)hh*L_*HDIM + (size_t)k*HDIM + d) = o;
    return;
  }
  bid -= CACHE_;
  {
    const int nkb = (CACHE_ + 63) >> 6;
    const int kbi = bid % nkb;
    const int rest = bid / nkb;
    const int dbi = rest & 3;
    const int hh  = rest >> 2;
    const int kb0 = kbi * 64, db0 = dbi * 32;
    const int kk = t >> 2, dd = (t & 3) * 8;
    const int k = kb0 + kk;
    if (k < CACHE_){
      const float* p = v_cache + (size_t)k*DIMN + hh*HDIM + db0 + dd;
      float4 a = ((const float4*)p)[0], b = ((const float4*)p)[1];
      tile[dd+0][kk] = f2bf(a.x); tile[dd+1][kk] = f2bf(a.y);
      tile[dd+2][kk] = f2bf(a.z); tile[dd+3][kk] = f2bf(a.w);
      tile[dd+4][kk] = f2bf(b.x); tile[dd+5][kk] = f2bf(b.y);
      tile[dd+6][kk] = f2bf(b.z); tile[dd+7][kk] = f2bf(b.w);
    }
    __syncthreads();
    const int d = t >> 3, k0 = (t & 7) * 8;
    unsigned short* dst = vtb + (size_t)hh*HDIM*L_ + (size_t)(db0+d)*L_ + kb0 + k0;
    if (kb0 + k0 + 8 <= CACHE_){
      *(u16x8*)dst = *(const u16x8*)&tile[d][k0];
    } else {
      #pragma unroll
      for (int e=0;e<8;++e) if (kb0 + k0 + e < CACHE_) dst[e] = tile[d][k0+e];
    }
  }
}

// ---------------- merged post-projection: rmsnorm+RoPE (Q/K) + V transpose ----------
__global__ __launch_bounds__(256) void postproj_kernel(const unsigned short* __restrict__ lin0,
    const unsigned short* __restrict__ lin1, const unsigned short* __restrict__ lin2,
    const float* __restrict__ gq, const float* __restrict__ gk,
    const float* __restrict__ freqs, const int* __restrict__ cur,
    unsigned short* __restrict__ qb, unsigned short* __restrict__ kb,
    unsigned short* __restrict__ vtb,
    int S_, int CACHE_, int L_, float qsc){
  __shared__ __align__(16) unsigned short tile[32][72];
  __shared__ float red[4];
  const int t = threadIdx.x;
  int bid = blockIdx.x;
  if (bid < 2*S_){
    const int path = (bid >= S_) ? 1 : 0;
    const int q = bid - path*S_;
    const unsigned short* lin = path ? lin1 : lin0;
    const float* g = path ? gk : gq;
    unsigned short* out = path ? kb : qb;
    const size_t head_stride = path ? (size_t)L_*HDIM : (size_t)S_*HDIM;
    const int row_off = path ? CACHE_ : 0;
    const float oscale = path ? 1.0f : qsc;
    u16x8 v = *(const u16x8*)(lin + (size_t)q*DIMN + t*8);
    float x[8];
    #pragma unroll
    for (int e=0;e<8;++e) x[e] = bf2f(v[e]);
    float ss = 0.f;
    #pragma unroll
    for (int e=0;e<8;++e) ss += x[e]*x[e];
    for (int m=1;m<64;m<<=1) ss += __shfl_xor(ss, m);
    if ((t & 63) == 0) red[t>>6] = ss;
    __syncthreads();
    const float tot = red[0]+red[1]+red[2]+red[3];
    const float rstd = rsqrtf(tot * (1.0f/2048.0f) + 1e-6f);
    const int n0 = t*8;
    float xr[8];
    #pragma unroll
    for (int e=0;e<8;++e) xr[e] = x[e] * rstd * g[n0+e];
    const int pos = cur[0] + q;
    const int hh = n0 >> 7, d0 = n0 & 127;
    const float* fr = freqs + (size_t)pos * HDIM;
    float o[8];
    #pragma unroll
    for (int p=0;p<4;++p){
      const int j = (d0>>1) + p;
      const float c = fr[j], s = fr[64+j];
      o[2*p]   = xr[2*p]*c - xr[2*p+1]*s;
      o[2*p+1] = xr[2*p+1]*c + xr[2*p]*s;
    }
    u16x8 ov;
    #pragma unroll
    for (int e=0;e<8;++e) ov[e] = f2bf(o[e]*oscale);
    *(u16x8*)(out + (size_t)hh*head_stride + (size_t)(q+row_off)*HDIM + d0) = ov;
    return;
  }
  bid -= 2*S_;
  {
    const int nkb = (S_ + 63) >> 6;
    const int kbi = bid % nkb;
    const int rest = bid / nkb;
    const int dbi = rest & 3;
    const int hh  = rest >> 2;
    const int kb0 = kbi * 64, db0 = dbi * 32;
    const int kk = t >> 2, dd = (t & 3) * 8;
    const int k = kb0 + kk;
    if (k < S_){
      u16x8 a = *(const u16x8*)(lin2 + (size_t)k*DIMN + hh*HDIM + db0 + dd);
      #pragma unroll
      for (int e=0;e<8;++e) tile[dd+e][kk] = a[e];
    }
    __syncthreads();
    const int d = t >> 3, k0 = (t & 7) * 8;
    unsigned short* dst = vtb + (size_t)hh*HDIM*L_ + (size_t)(db0+d)*L_ + CACHE_ + kb0 + k0;
    if (kb0 + k0 + 8 <= S_){
      *(u16x8*)dst = *(const u16x8*)&tile[d][k0];
    } else {
      #pragma unroll
      for (int e=0;e<8;++e) if (kb0 + k0 + e < S_) dst[e] = tile[d][k0+e];
    }
  }
}

// ---------------- C[M,N] = A[M,K] * B[N,K]^T + bias, bf16 in fp32 out ----------------
__global__ __launch_bounds__(256,2) void gemm_bt(const unsigned short* __restrict__ A,
    const unsigned short* __restrict__ B, const float* __restrict__ bias,
    float* __restrict__ C, int M, int N, int K){
  __shared__ __align__(16) unsigned short As[2][128*64];
  __shared__ __align__(16) unsigned short Bs[2][128*64];
  const int mb = (M + 127) >> 7;
  const int swz = xcd_swz(blockIdx.x, gridDim.x);
  const int bx = swz / mb, by = swz % mb;
  const int t = threadIdx.x;
  const int w = t >> 6, lane = t & 63, lh = lane >> 4, ll = lane & 15;
  const int wr = w >> 1, wc = w & 1;
  const int m0 = by * 128, n0 = bx * 128;
  const int srow = t >> 3;
  const int scb  = (t & 7) * 16;
  const int swc  = (scb ^ ((srow & 7) << 4)) >> 1;
  int arow[4]; size_t brow[4];
  #pragma unroll
  for (int c=0;c<4;++c){
    int r = m0 + c*32 + srow; if (r >= M) r = M-1;
    arow[c] = r;
    brow[c] = (size_t)(n0 + c*32 + srow);
  }
  const int xsw = (ll & 7) << 4;
  f32x4 acc[4][4] = {};
  const int nk = K >> 6;
  auto stage = [&](int b, int kt){
    const int k0 = kt << 6;
    #pragma unroll
    for (int c=0;c<4;++c){
      gl_lds16(A + (size_t)arow[c]*K + k0 + swc, (char*)As[b] + c*4096 + w*1024);
      gl_lds16(B + brow[c]*K       + k0 + swc, (char*)Bs[b] + c*4096 + w*1024);
    }
  };
  stage(0, 0);
  asm volatile("s_waitcnt vmcnt(0)" ::: "memory");
  __syncthreads();
  int cur = 0;
  for (int kt = 0; kt < nk; ++kt){
    if (kt + 1 < nk) stage(cur ^ 1, kt + 1);
    #pragma unroll
    for (int kk=0;kk<2;++kk){
      const int cb = kk*64 + lh*16;
      bfx8 a[4], b[4];
      #pragma unroll
      for (int i=0;i<4;++i)
        a[i] = *(const bfx8*)((const char*)As[cur] + (wr*64 + i*16 + ll)*128 + (cb ^ xsw));
      #pragma unroll
      for (int j=0;j<4;++j)
        b[j] = *(const bfx8*)((const char*)Bs[cur] + (wc*64 + j*16 + ll)*128 + (cb ^ xsw));
      __builtin_amdgcn_s_setprio(1);
      #pragma unroll
      for (int i=0;i<4;++i)
        #pragma unroll
        for (int j=0;j<4;++j)
          acc[i][j] = MFMA16(a[i], b[j], acc[i][j]);
      __builtin_amdgcn_s_setprio(0);
    }
    asm volatile("s_waitcnt vmcnt(0)" ::: "memory");
    __syncthreads();
    cur ^= 1;
  }
  #pragma unroll
  for (int i=0;i<4;++i){
    #pragma unroll
    for (int j=0;j<4;++j){
      const int col = n0 + wc*64 + j*16 + ll;
      const float bb = bias[col];
      #pragma unroll
      for (int r=0;r<4;++r){
        const int row = m0 + wr*64 + i*16 + lh*4 + r;
        if (row < M) C[(size_t)row*N + col] = acc[i][j][r] + bb;
      }
    }
  }
}

// ---------------- fused QKV gemm (1D grid + XCD swizzle); dbuf; bf16 out ----------------
__global__ __launch_bounds__(256,2) void gemm_qkv(const unsigned short* __restrict__ A,
    const unsigned short* __restrict__ B0, const unsigned short* __restrict__ B1,
    const unsigned short* __restrict__ B2, const float* __restrict__ g0,
    const float* __restrict__ g1, const float* __restrict__ g2,
    unsigned short* __restrict__ C0, unsigned short* __restrict__ C1,
    unsigned short* __restrict__ C2, int M, int N, int K){
  const int mb = (M + 127) >> 7;
  const int nxt = N >> 7;
  const int per = nxt * mb;
  const int swz = xcd_swz(blockIdx.x, gridDim.x);
  const int zz = swz / per;
  const int rem = swz - zz * per;
  const int bx = rem / mb, by = rem % mb;
  const unsigned short* B = (zz==0) ? B0 : (zz==1) ? B1 : B2;
  const float* bias       = (zz==0) ? g0 : (zz==1) ? g1 : g2;
  unsigned short* C       = (zz==0) ? C0 : (zz==1) ? C1 : C2;
  __shared__ __align__(16) unsigned short As[2][128*64];
  __shared__ __align__(16) unsigned short Bs[2][128*64];
  const int t = threadIdx.x;
  const int w = t >> 6, lane = t & 63, lh = lane >> 4, ll = lane & 15;
  const int wr = w >> 1, wc = w & 1;
  const int m0 = by * 128, n0 = bx * 128;
  const int srow = t >> 3;
  const int scb  = (t & 7) * 16;
  const int swc  = (scb ^ ((srow & 7) << 4)) >> 1;
  int arow[4]; size_t brow[4];
  #pragma unroll
  for (int c=0;c<4;++c){
    int r = m0 + c*32 + srow; if (r >= M) r = M-1;
    arow[c] = r;
    brow[c] = (size_t)(n0 + c*32 + srow);
  }
  const int xsw = (ll & 7) << 4;
  f32x4 acc[4][4] = {};
  const int nk = K >> 6;
  auto stage = [&](int b, int kt){
    const int k0 = kt << 6;
    #pragma unroll
    for (int c=0;c<4;++c){
      gl_lds16(A + (size_t)arow[c]*K + k0 + swc, (char*)As[b] + c*4096 + w*1024);
      gl_lds16(B + brow[c]*K       + k0 + swc, (char*)Bs[b] + c*4096 + w*1024);
    }
  };
  stage(0, 0);
  asm volatile("s_waitcnt vmcnt(0)" ::: "memory");
  __syncthreads();
  int cur = 0;
  for (int kt = 0; kt < nk; ++kt){
    if (kt + 1 < nk) stage(cur ^ 1, kt + 1);
    #pragma unroll
    for (int kk=0;kk<2;++kk){
      const int cb = kk*64 + lh*16;
      bfx8 a[4], b[4];
      #pragma unroll
      for (int i=0;i<4;++i)
        a[i] = *(const bfx8*)((const char*)As[cur] + (wr*64 + i*16 + ll)*128 + (cb ^ xsw));
      #pragma unroll
      for (int j=0;j<4;++j)
        b[j] = *(const bfx8*)((const char*)Bs[cur] + (wc*64 + j*16 + ll)*128 + (cb ^ xsw));
      __builtin_amdgcn_s_setprio(1);
      #pragma unroll
      for (int i=0;i<4;++i)
        #pragma unroll
        for (int j=0;j<4;++j)
          acc[i][j] = MFMA16(a[i], b[j], acc[i][j]);
      __builtin_amdgcn_s_setprio(0);
    }
    asm volatile("s_waitcnt vmcnt(0)" ::: "memory");
    __syncthreads();
    cur ^= 1;
  }
  #pragma unroll
  for (int i=0;i<4;++i){
    #pragma unroll
    for (int j=0;j<4;++j){
      const int col = n0 + wc*64 + j*16 + ll;
      const float bb = bias[col];
      #pragma unroll
      for (int r=0;r<4;++r){
        const int row = m0 + wr*64 + i*16 + lh*4 + r;
        if (row < M) C[(size_t)row*N + col] = f2bf(acc[i][j][r] + bb);
      }
    }
  }
}

// ---------------- flash attention: 4 waves, 32x32x16 MFMA, gl_lds dbuf staging --------
__global__ __launch_bounds__(256,2) void attn_kernel(const unsigned short* __restrict__ Q,
    const unsigned short* __restrict__ K, const unsigned short* __restrict__ VT,
    unsigned short* __restrict__ O, float* __restrict__ pacc, float* __restrict__ pml,
    int S_, int L_, int CLn, int nx, int nsplit){
  __shared__ __align__(16) unsigned short Ks[2][64*128];
  __shared__ __align__(16) unsigned short Vs[2][128*64];
  __shared__ __align__(16) unsigned short Ps[4][32*64];
  const int nwg = gridDim.x;
  const int swzid = (blockIdx.x & 7)*(nwg >> 3) + (blockIdx.x >> 3);
  const int xq = swzid % nx;
  const int rest = swzid / nx;
  const int hh = rest % NH;
  const int z  = rest / NH;
  const int q0 = xq * 128;
  const int t = threadIdx.x, w = t >> 6, lane = t & 63;
  const int l31 = lane & 31, h = lane >> 5;
  char* Pw = (char*)Ps[w];
  const int xswp = (l31 & 7) << 4;
  const unsigned short* Qh = Q  + (size_t)hh*S_*HDIM;
  const unsigned short* Kh = K  + (size_t)hh*L_*HDIM;
  const unsigned short* Vh = VT + (size_t)hh*HDIM*L_;
  const int wrow0 = q0 + w*32;
  const int myq = wrow0 + l31;
  bfx8 qf[8];
  {
    int qr = myq; if (qr >= S_) qr = S_ - 1;
    #pragma unroll
    for (int kk=0;kk<8;++kk)
      qf[kk] = *(const bfx8*)(Qh + (size_t)qr*HDIM + kk*16 + h*8);
  }
  f32x16 acc[4] = {};
  float m_st = -1e20f, l_st = 0.f;
  int qlast = q0 + 127; if (qlast >= S_) qlast = S_ - 1;
  const int kend = CLn + qlast + 1;
  const int nt = (kend + 63) >> 6;
  const int tps = (nt + nsplit - 1) / nsplit;
  const int t0 = z * tps;
  int t1 = t0 + tps; if (t1 > nt) t1 = nt;
  const int ksrow = t >> 4;
  const int kswc  = (((t & 15)*16) ^ ((ksrow & 7) << 4)) >> 1;
  const int vsrow = t >> 3;
  const int vswc  = (((t & 7)*16) ^ ((vsrow & 7) << 4)) >> 1;

  auto stage = [&](int b, int ktile){
    const int kv0 = ktile << 6;
    #pragma unroll
    for (int c=0;c<4;++c)
      gl_lds16(Kh + (size_t)(kv0 + c*16 + ksrow)*HDIM + kswc, (char*)Ks[b] + c*4096 + w*1024);
    #pragma unroll
    for (int c=0;c<4;++c)
      gl_lds16(Vh + (size_t)(c*32 + vsrow)*L_ + kv0 + vswc, (char*)Vs[b] + c*4096 + w*1024);
  };

  if (t0 < t1) stage(0, t0);
  asm volatile("s_waitcnt vmcnt(0)" ::: "memory");
  __syncthreads();
  const int krow0 = l31,      koff0 = (krow0 & 7) << 4;
  const int krow1 = 32 + l31, koff1 = (krow1 & 7) << 4;
  int cur = 0;
  for (int kt = t0; kt < t1; ++kt){
    const int kv0 = kt << 6;
    if (kt + 1 < t1) stage(cur ^ 1, kt + 1);
    const char* Kc = (const char*)Ks[cur];
    const char* Vc = (const char*)Vs[cur];
    f32x16 sc0 = {}, sc1 = {};
    __builtin_amdgcn_s_setprio(1);
    #pragma unroll
    for (int kk=0;kk<8;++kk){
      const int cb = kk*32 + h*16;
      bfx8 kf0 = *(const bfx8*)(Kc + krow0*256 + (cb ^ koff0));
      bfx8 kf1 = *(const bfx8*)(Kc + krow1*256 + (cb ^ koff1));
      sc0 = MFMA32(kf0, qf[kk], sc0);
      sc1 = MFMA32(kf1, qf[kk], sc1);
    }
    __builtin_amdgcn_s_setprio(0);
    if (kv0 + 63 > CLn + wrow0){
      const int lim = CLn + myq;
      #pragma unroll
      for (int r=0;r<16;++r){
        const int kl = (r&3) + 8*(r>>2) + 4*h;
        if (kv0 + kl      > lim) sc0[r] = -1e30f;
        if (kv0 + 32 + kl > lim) sc1[r] = -1e30f;
      }
    }
    // row max: v_max3-friendly triples + cross-half
    float mt = sc0[0];
    #pragma unroll
    for (int r=1;r<15;r+=2) mt = fmaxf(fmaxf(sc0[r], sc0[r+1]), mt);
    mt = fmaxf(sc0[15], mt);
    #pragma unroll
    for (int r=0;r<16;r+=2) mt = fmaxf(fmaxf(sc1[r], sc1[r+1]), mt);
    mt = fmaxf(mt, __shfl_xor(mt, 32));
    mt = fmaxf(mt, -1e20f);
    if (!__all(mt - m_st <= 11.54f)){
      const float mn = fmaxf(m_st, mt);
      const float corr = exp2f(m_st - mn);
      m_st = mn;
      l_st *= corr;
      #pragma unroll
      for (int r=0;r<16;++r){
        const int qrow = (r&3) + 8*(r>>2) + 4*h;
        const float ca = __shfl(corr, qrow);
        #pragma unroll
        for (int db=0;db<4;++db) acc[db][r] *= ca;
      }
    }
    float rs = 0.f;
    #pragma unroll
    for (int r=0;r<16;++r){
      const float p0 = exp2f(sc0[r] - m_st);
      const float p1 = exp2f(sc1[r] - m_st);
      sc0[r] = p0; sc1[r] = p1;
      rs += p0 + p1;
    }
    rs += __shfl_xor(rs, 32);
    l_st += rs;
    #pragma unroll
    for (int i=0;i<4;++i){
      bf16x4 p0 = { (__bf16)sc0[4*i], (__bf16)sc0[4*i+1], (__bf16)sc0[4*i+2], (__bf16)sc0[4*i+3] };
      bf16x4 p1 = { (__bf16)sc1[4*i], (__bf16)sc1[4*i+1], (__bf16)sc1[4*i+2], (__bf16)sc1[4*i+3] };
      const int kb0b = (8*i + 4*h) * 2;
      *(bf16x4*)(Pw + l31*128 + (kb0b        ^ xswp)) = p0;
      *(bf16x4*)(Pw + l31*128 + ((64 + kb0b) ^ xswp)) = p1;
    }
    __builtin_amdgcn_s_setprio(1);
    #pragma unroll
    for (int s=0;s<4;++s){
      bfx8 pa = *(const bfx8*)(Pw + l31*128 + ((s*32 + h*16) ^ xswp));
      const int vb = s*32 + h*16;
      #pragma unroll
      for (int db=0;db<4;++db){
        const int vrow = db*32 + l31;
        bfx8 vf = *(const bfx8*)(Vc + vrow*128 + (vb ^ ((vrow & 7) << 4)));
        acc[db] = MFMA32(pa, vf, acc[db]);
      }
    }
    __builtin_amdgcn_s_setprio(0);
    asm volatile("s_waitcnt vmcnt(0)" ::: "memory");
    __syncthreads();
    cur ^= 1;
  }
  if (nsplit == 1){
    const float linv = 1.0f / l_st;
    #pragma unroll
    for (int r=0;r<16;++r){
      const int qrow = (r&3) + 8*(r>>2) + 4*h;
      const float inv = __shfl(linv, qrow);
      const int qr = wrow0 + qrow;
      if (qr < S_){
        #pragma unroll
        for (int db=0;db<4;++db)
          O[(size_t)qr*DIMN + hh*HDIM + db*32 + l31] = f2bf(acc[db][r]*inv);
      }
    }
  } else {
    #pragma unroll
    for (int r=0;r<16;++r){
      const int qrow = (r&3) + 8*(r>>2) + 4*h;
      const int qr = wrow0 + qrow;
      if (qr < S_){
        const size_t rid = ((size_t)z*NH + hh)*S_ + qr;
        float* dst = pacc + rid*128;
        #pragma unroll
        for (int db=0;db<4;++db) dst[db*32 + l31] = acc[db][r];
      }
    }
    if (lane < 32 && myq < S_){
      const size_t rid2 = ((size_t)z*NH + hh)*S_ + myq;
      pml[rid2*2]   = m_st;
      pml[rid2*2+1] = l_st;
    }
  }
}

// ---------------- combine partials -> ob bf16 (exp2 domain m) ----------------
__global__ __launch_bounds__(256) void combine_kernel(const float* __restrict__ pacc,
    const float* __restrict__ pml, unsigned short* __restrict__ ob, int S_, int nsplit){
  const int t = threadIdx.x;
  const int rid = blockIdx.x*2 + (t >> 7);   // hh*S_+q
  if (rid >= S_*NH) return;
  const int d = t & 127;
  const int hh = rid / S_;
  const int q  = rid - hh*S_;
  float M = -1e20f;
  for (int s=0; s<nsplit; ++s)
    M = fmaxf(M, pml[((size_t)s*NH*S_ + rid)*2]);
  float lt = 0.f, o = 0.f;
  for (int s=0; s<nsplit; ++s){
    const float m = pml[((size_t)s*NH*S_ + rid)*2];
    const float l = pml[((size_t)s*NH*S_ + rid)*2 + 1];
    const float wgt = exp2f(m - M);
    lt += l * wgt;
    o  += pacc[((size_t)s*NH*S_ + rid)*128 + d] * wgt;
  }
  if (lt == 0.f) lt = 1.f;
  ob[(size_t)q*DIMN + hh*HDIM + d] = f2bf(o / lt);
}

extern "C" void kernel_launch(void* const* d_in, const int* in_sizes, int n_in,
                              void* d_out, int out_size, void* d_ws, size_t ws_size,
                              hipStream_t stream){
  const float* x       = (const float*)d_in[0];
  const float* freqs   = (const float*)d_in[1];
  const float* k_cache = (const float*)d_in[2];
  const float* v_cache = (const float*)d_in[3];
  const float* Wq = (const float*)d_in[4];
  const float* bq = (const float*)d_in[5];
  const float* Wk = (const float*)d_in[6];
  const float* bk = (const float*)d_in[7];
  const float* Wv = (const float*)d_in[8];
  const float* bv = (const float*)d_in[9];
  const float* Wo = (const float*)d_in[10];
  const float* bo = (const float*)d_in[11];
  const float* gq = (const float*)d_in[12];
  const float* gk = (const float*)d_in[13];
  const int*   cur = (const int*)d_in[14];

  const int S = in_sizes[0] / DIMN;
  const int CACHE_ = in_sizes[2] / DIMN;
  const int L = CACHE_ + S;
  const int CLn = L - S;

  auto al = [](size_t n){ return (n + 255) & ~(size_t)255; };
  char* base = (char*)d_ws;
  size_t off = 0;
  auto take = [&](size_t n){ char* r = base + off; off += al(n); return r; };
  // persistent:
  unsigned short* xb  = (unsigned short*)take((size_t)S*DIMN*2);
  unsigned short* Wob = (unsigned short*)take((size_t)DIMN*DIMN*2);
  unsigned short* qb  = (unsigned short*)take((size_t)NH*S*HDIM*2);
  unsigned short* kb  = (unsigned short*)take((size_t)NH*L*HDIM*2);
  unsigned short* vtb = (unsigned short*)take((size_t)NH*HDIM*L*2);
  unsigned short* ob  = (unsigned short*)take((size_t)S*DIMN*2);
  const size_t ubase = off;
  // union pool A: transients (dead before attn): lin0/1/2 (bf16) + Wq/Wk/Wv (bf16)
  const size_t l_sz = al((size_t)S*DIMN*2);
  const size_t w_sz = al((size_t)DIMN*DIMN*2);
  unsigned short* lin0 = (unsigned short*)(base + ubase);
  unsigned short* lin1 = (unsigned short*)(base + ubase + l_sz);
  unsigned short* lin2 = (unsigned short*)(base + ubase + 2*l_sz);
  unsigned short* Wqb  = (unsigned short*)(base + ubase + 3*l_sz);
  unsigned short* Wkb  = (unsigned short*)(base + ubase + 3*l_sz + w_sz);
  unsigned short* Wvb  = (unsigned short*)(base + ubase + 3*l_sz + 2*w_sz);
  const size_t trans_sz = 3*l_sz + 3*w_sz;
  // union pool B: attention partials
  auto pool_sz = [&](int ns){
    return al((size_t)ns*NH*S*HDIM*4) + al((size_t)ns*NH*S*2*4);
  };
  int nsplit = 1;
  if (ubase + (trans_sz > pool_sz(4) ? trans_sz : pool_sz(4)) <= ws_size) nsplit = 4;
  else if (ubase + (trans_sz > pool_sz(2) ? trans_sz : pool_sz(2)) <= ws_size) nsplit = 2;
  if (ubase + trans_sz > ws_size) return;
  float* pacc = (float*)(base + ubase);
  float* pml  = (float*)(base + ubase + al((size_t)nsplit*NH*S*HDIM*4));

  // merged prep: x/W casts + kcache + v_cache transpose
  const int WB = (DIMN*DIMN/8)/256;
  const int nkb = (CACHE_ + 63) >> 6;
  const int prep_blocks = S + 4*WB + CACHE_ + nkb*4*NH;
  prep_kernel<<<prep_blocks, 256, 0, stream>>>(x, Wq, Wk, Wv, Wo, k_cache, v_cache,
                                               xb, Wqb, Wkb, Wvb, Wob, kb, vtb,
                                               S, CACHE_, L);

  const int mb = (S+127)/128;
  gemm_qkv<<<(DIMN/128)*mb*3, 256, 0, stream>>>(xb, Wqb, Wkb, Wvb, bq, bk, bv,
                                                lin0, lin1, lin2, S, DIMN, DIMN);
  // merged post-projection: Q/K norm+RoPE + V transpose in one dispatch
  const float qsc = 0.08838834764831845f * 1.4426950408889634f;
  const int nkb2 = (S + 63) >> 6;
  const int pp_blocks = 2*S + nkb2*4*NH;
  postproj_kernel<<<pp_blocks, 256, 0, stream>>>(lin0, lin1, lin2, gq, gk, freqs, cur,
                                                 qb, kb, vtb, S, CACHE_, L, qsc);

  const int nx = (S+127)/128;
  attn_kernel<<<nx*NH*nsplit, 256, 0, stream>>>(qb, kb, vtb, ob,
                                                pacc, pml, S, L, CLn, nx, nsplit);
  if (nsplit > 1)
    combine_kernel<<<(S*NH+1)/2, 256, 0, stream>>>(pacc, pml, ob, S, nsplit);
  gemm_bt<<<(DIMN/128)*mb, 256, 0, stream>>>(ob, Wob, bo, (float*)d_out, S, DIMN, DIMN);
}